// Round 2
// baseline (1158.477 us; speedup 1.0000x reference)
//
#include <hip/hip_runtime.h>
#include <hip/hip_bf16.h>
#include <stdint.h>

// LMHA: linear multi-head attention (elu+1 feature map), S=2048 B=16 D=1024 H=8 dh=128
// Pipeline: prep_h -> pack_w -> gemm_qkv (fused bias+elu+scatter) -> kv_kernel (kv state + z)
//           -> attn_kernel (num, den, divide) -> gemm_out (+bo)
// All GEMMs: bt-form C[m][n] = sum_k A[m][k] * W[n][k], bf16 in / fp32 acc,
// 128x128 block tile, 4 waves (2x2 of 64x64), MFMA 16x16x32 bf16.
// R1: m97 structure (global_load_lds w=16, linear LDS). Result: latency-bound, 14% MfmaUtil.
// R2: (a) 2-phase LDS double-buffer: stage(next) issued BEFORE consuming(cur), ONE
//     __syncthreads() per K-step -> load latency hides under ds_read+MFMA.
//     (b) XCD-chunked block swizzle (bijective, nwg%8==0): consecutive blocks on an
//     XCD share the A-panel -> L2-hit instead of LLC/HBM re-fetch (3.2 GB staged vs
//     70 MB working set was thrashing per-XCD 4MB L2s).

typedef __bf16 bf16x8 __attribute__((ext_vector_type(8)));
typedef float f32x4 __attribute__((ext_vector_type(4)));

#define S_LEN 2048
#define B_SZ  16
#define D_MOD 1024
#define N_H   8
#define D_H   128

__device__ __forceinline__ short f2bf(float f) {
  __bf16 b = (__bf16)f;
  return __builtin_bit_cast(short, b);
}
__device__ __forceinline__ float bf2f(short s) {
  return (float)__builtin_bit_cast(__bf16, s);
}

// async global->LDS, 16B per lane. Dest must be wave-uniform base + lane*16.
__device__ __forceinline__ void gload_lds16(const short* g, short* l) {
  __builtin_amdgcn_global_load_lds(
      (__attribute__((address_space(1))) void*)(g),
      (__attribute__((address_space(3))) void*)(l), 16, 0, 0);
}

// ---------------- prep: h = bf16(x + pos_encoding) ----------------
__global__ void prep_h(const float* __restrict__ x, short* __restrict__ h) {
  size_t idx8 = (size_t)blockIdx.x * blockDim.x + threadIdx.x; // 8 elems / thread
  size_t base = idx8 * 8;                                      // < 33,554,432
  int d = (int)(base & 1023);
  int r = (int)(base >> 10);
  int s = r >> 4; // row = s*B + b
  float4 v0 = *(const float4*)(x + base);
  float4 v1 = *(const float4*)(x + base + 4);
  float vs[8] = {v0.x, v0.y, v0.z, v0.w, v1.x, v1.y, v1.z, v1.w};
  const float kdiv = -9.210340371976184f / 1024.0f; // -ln(10000)/D
  bf16x8 ov;
#pragma unroll
  for (int t = 0; t < 8; ++t) {
    int dc = d + t;
    float div = __expf((float)(dc & ~1) * kdiv);
    float ang = (float)s * div;
    float pe = (dc & 1) ? __cosf(ang) : __sinf(ang);
    ov[t] = (__bf16)(vs[t] + pe);
  }
  *(bf16x8*)(h + base) = ov;
}

// ---------------- pack weights to bf16: [Wq;Wk;Wv;Wo] = [4096,1024] ----------------
__global__ void pack_w(const float* __restrict__ Wq, const float* __restrict__ Wk,
                       const float* __restrict__ Wv, const float* __restrict__ Wo,
                       short* __restrict__ Wcat) {
  size_t i4 = (size_t)blockIdx.x * blockDim.x + threadIdx.x;
  size_t base = i4 * 4; // < 4,194,304
  const float* src;
  size_t off;
  if (base < 1048576)      { src = Wq; off = base; }
  else if (base < 2097152) { src = Wk; off = base - 1048576; }
  else if (base < 3145728) { src = Wv; off = base - 2097152; }
  else                     { src = Wo; off = base - 3145728; }
  float4 v = *(const float4*)(src + off);
  alignas(8) short o[4] = {f2bf(v.x), f2bf(v.y), f2bf(v.z), f2bf(v.w)};
  *(uint2*)(Wcat + base) = *(const uint2*)o;
}

// ---------------- shared GEMM core: 128x128 tile, bt-form, 2-phase dbuf ----------
// A, W already offset to this block's 128-row bases. LDS linear [2][128][32] shorts.
// Per BK=32 step: issue next tile's 4x global_load_lds_dwordx4, then 8 ds_read_b128
// + 16 MFMA from current buffer, then ONE __syncthreads() (vmcnt0+lgkmcnt0+barrier).
template <int K>
__device__ __forceinline__ void gemm_core_128(const short* __restrict__ A,
                                              const short* __restrict__ W,
                                              short* As, short* Ws, // each [2*128*32]
                                              f32x4 (&acc)[4][4]) {
  const int tid = threadIdx.x;
  const int c8 = tid & 3, r0 = tid >> 2; // stage: row r0 (0..63), col c8*8
  const int lane = tid & 63;
  const int wm = (tid >> 6) & 1, wn = tid >> 7;
  const int l15 = lane & 15, quad = lane >> 4;

  const short* ga0 = A + (size_t)r0 * K + c8 * 8;
  const short* ga1 = ga0 + (size_t)64 * K;
  const short* gw0 = W + (size_t)r0 * K + c8 * 8;
  const short* gw1 = gw0 + (size_t)64 * K;
  const int soff = r0 * 32 + c8 * 8; // bytes = tid*16 -> wave-uniform base + lane*16

  // prologue: stage step 0 into buffer 0
  gload_lds16(ga0, As + soff);
  gload_lds16(ga1, As + soff + 64 * 32);
  gload_lds16(gw0, Ws + soff);
  gload_lds16(gw1, Ws + soff + 64 * 32);
  __syncthreads();

  int cur = 0;
  for (int k0 = 0; k0 < K; k0 += 32) {
    const int nxt = cur ^ 1;
    if (k0 + 32 < K) { // issue next-tile loads; they fly during this step's compute
      const int nb = nxt * (128 * 32);
      gload_lds16(ga0 + k0 + 32, As + nb + soff);
      gload_lds16(ga1 + k0 + 32, As + nb + soff + 64 * 32);
      gload_lds16(gw0 + k0 + 32, Ws + nb + soff);
      gload_lds16(gw1 + k0 + 32, Ws + nb + soff + 64 * 32);
    }
    const short* Asb = As + cur * (128 * 32);
    const short* Wsb = Ws + cur * (128 * 32);
    bf16x8 af[4], wf[4];
#pragma unroll
    for (int i = 0; i < 4; ++i)
      af[i] = *(const bf16x8*)&Asb[(wm * 64 + i * 16 + l15) * 32 + quad * 8];
#pragma unroll
    for (int j = 0; j < 4; ++j)
      wf[j] = *(const bf16x8*)&Wsb[(wn * 64 + j * 16 + l15) * 32 + quad * 8];
#pragma unroll
    for (int i = 0; i < 4; ++i)
#pragma unroll
      for (int j = 0; j < 4; ++j)
        acc[i][j] = __builtin_amdgcn_mfma_f32_16x16x32_bf16(af[i], wf[j], acc[i][j], 0, 0, 0);
    // one barrier per step: guarantees (lgkmcnt0) all reads of cur done and
    // (vmcnt0) all writes into nxt done before next iter overwrites cur.
    __syncthreads();
    cur = nxt;
  }
}

// ---------------- GEMM1: qkv = h @ Wqkv^T, fused bias + elu+1, scatter ----------------
// pq  -> [B,H,S,dh]   (s-major, for num GEMM A-operand)
// pkT -> [B,H,dh,S]   (transposed, K-contiguous for kv GEMM)
// vT  -> [B,H,dh,S]
__launch_bounds__(256)
__global__ void gemm_qkv(const short* __restrict__ h, const short* __restrict__ Wqkv,
                         const float* __restrict__ bq, const float* __restrict__ bk,
                         const float* __restrict__ bv,
                         short* __restrict__ pq, short* __restrict__ pkT,
                         short* __restrict__ vT) {
  __shared__ alignas(16) short As[2 * 128 * 32];
  __shared__ alignas(16) short Ws[2 * 128 * 32];
  // XCD-chunked swizzle: nwg = 24*256 = 6144, 6144%8==0, chunk = 768.
  // Consecutive blocks on one XCD share the same A (h) 128-row panel.
  int lin = blockIdx.y * 24 + blockIdx.x;      // bn-fast linear id
  lin = (lin & 7) * 768 + (lin >> 3);          // bijective chunked remap
  const int bn = lin % 24;                     // 0..23  (N = 3072)
  const int bm = lin / 24;                     // 0..255 (M = 32768)
  const int rowBase = bm * 128, colBase = bn * 128;

  f32x4 acc[4][4] = {};
  gemm_core_128<1024>(h + (size_t)rowBase * 1024, Wqkv + (size_t)colBase * 1024, As, Ws, acc);

  const int tid = threadIdx.x;
  const int lane = tid & 63;
  const int wm = (tid >> 6) & 1, wn = tid >> 7;
  const int l15 = lane & 15, quad = lane >> 4;

  const int p = colBase >> 10;        // 0:q 1:k 2:v (uniform per block)
  const int hh = (colBase >> 7) & 7;  // head (uniform per block)
  const float* bias = (p == 0) ? bq : (p == 1) ? bk : bv;

#pragma unroll
  for (int j = 0; j < 4; ++j) {
    const int e = wn * 64 + j * 16 + l15; // 0..127
    const float bval = bias[hh * 128 + e];
#pragma unroll
    for (int i = 0; i < 4; ++i) {
#pragma unroll
      for (int r = 0; r < 4; ++r) {
        int mloc = wm * 64 + i * 16 + quad * 4 + r;
        int grow = rowBase + mloc;
        int s = grow >> 4, b = grow & 15;
        float v = acc[i][j][r] + bval;
        if (p == 0) {
          float u = v > 0.f ? v + 1.f : __expf(v); // elu(v)+1
          pq[(((size_t)b * N_H + hh) * S_LEN + s) * D_H + e] = f2bf(u);
        } else if (p == 1) {
          float u = v > 0.f ? v + 1.f : __expf(v);
          pkT[(((size_t)b * N_H + hh) * D_H + e) * S_LEN + s] = f2bf(u);
        } else {
          vT[(((size_t)b * N_H + hh) * D_H + e) * S_LEN + s] = f2bf(v);
        }
      }
    }
  }
}

// ---------------- kv state: kvT[bh][e][d] = sum_s vT[e][s]*pkT[d][s]; z[bh][d] ----------------
__launch_bounds__(256)
__global__ void kv_kernel(const short* __restrict__ pkT, const short* __restrict__ vT,
                          short* __restrict__ kvT, float* __restrict__ z) {
  __shared__ alignas(16) short As[2 * 128 * 32];
  __shared__ alignas(16) short Ws[2 * 128 * 32];
  const int bh = blockIdx.x; // 0..127
  const short* Abase = vT + (size_t)bh * D_H * S_LEN;  // rows = e
  const short* Wbase = pkT + (size_t)bh * D_H * S_LEN; // rows = d

  f32x4 acc[4][4] = {};
  gemm_core_128<2048>(Abase, Wbase, As, Ws, acc);

  const int tid = threadIdx.x;
  const int lane = tid & 63;
  const int wm = (tid >> 6) & 1, wn = tid >> 7;
  const int l15 = lane & 15, quad = lane >> 4;

#pragma unroll
  for (int j = 0; j < 4; ++j) {
    const int d = wn * 64 + j * 16 + l15;
#pragma unroll
    for (int i = 0; i < 4; ++i) {
#pragma unroll
      for (int r = 0; r < 4; ++r) {
        int e = wm * 64 + i * 16 + quad * 4 + r;
        kvT[(size_t)bh * (D_H * D_H) + (size_t)e * D_H + d] = f2bf(acc[i][j][r]);
      }
    }
  }
  // z[d] = sum_s pk[d][s]  (re-read pkT rows, L2-hot)
  __syncthreads();
  if (tid < 128) {
    const short* prow = Wbase + (size_t)tid * S_LEN;
    float sum = 0.f;
    for (int s = 0; s < S_LEN; s += 8) {
      bf16x8 vv = *(const bf16x8*)(prow + s);
#pragma unroll
      for (int t = 0; t < 8; ++t) sum += (float)vv[t];
    }
    z[bh * D_H + tid] = sum;
  }
}

// ---------------- num/den/divide: att = (pq @ kv) / (pq . z + eps) ----------------
__launch_bounds__(256)
__global__ void attn_kernel(const short* __restrict__ pq, const short* __restrict__ kvT,
                            const float* __restrict__ z, short* __restrict__ att) {
  __shared__ alignas(16) short As[2 * 128 * 32];
  __shared__ alignas(16) short Ws[2 * 128 * 32];
  __shared__ float den_lds[128];
  __shared__ float z_lds[128];
  // XCD-chunked swizzle: nwg = 16*128 = 2048, chunk = 256. Same-bh blocks cluster.
  int lin = blockIdx.y * 16 + blockIdx.x;
  lin = (lin & 7) * 256 + (lin >> 3);
  const int sx = lin & 15;
  const int bh = lin >> 4;         // 0..127
  const int s0 = sx * 128;         // 16 tiles over S
  const int tid = threadIdx.x;
  if (tid < 128) z_lds[tid] = z[bh * D_H + tid];

  const short* Abase = pq + ((size_t)bh * S_LEN + s0) * D_H; // rows = s
  const short* Wbase = kvT + (size_t)bh * (D_H * D_H);       // rows = e, cols = d

  f32x4 acc[4][4] = {};
  gemm_core_128<128>(Abase, Wbase, As, Ws, acc);

  // den[s] = sum_d pq[s][d] * z[d] + eps
  __syncthreads();
  if (tid < 128) {
    const short* prow = Abase + (size_t)tid * D_H;
    float sum = 0.f;
#pragma unroll
    for (int d = 0; d < D_H; d += 8) {
      bf16x8 vv = *(const bf16x8*)(prow + d);
#pragma unroll
      for (int t = 0; t < 8; ++t) sum += (float)vv[t] * z_lds[d + t];
    }
    den_lds[tid] = sum + 1e-6f;
  }
  __syncthreads();

  const int lane = tid & 63;
  const int wm = (tid >> 6) & 1, wn = tid >> 7;
  const int l15 = lane & 15, quad = lane >> 4;
  const int b = bh >> 3, hd = bh & 7;
#pragma unroll
  for (int j = 0; j < 4; ++j) {
    const int e = wn * 64 + j * 16 + l15;
#pragma unroll
    for (int i = 0; i < 4; ++i) {
#pragma unroll
      for (int r = 0; r < 4; ++r) {
        int mloc = wm * 64 + i * 16 + quad * 4 + r; // s_local
        float a = acc[i][j][r] / den_lds[mloc];
        att[((size_t)(s0 + mloc) * B_SZ + b) * D_MOD + hd * D_H + e] = f2bf(a);
      }
    }
  }
}

// ---------------- out = att @ Wo^T + bo (fp32 out) ----------------
__launch_bounds__(256)
__global__ void gemm_out(const short* __restrict__ att, const short* __restrict__ WoB,
                         const float* __restrict__ bo, float* __restrict__ out) {
  __shared__ alignas(16) short As[2 * 128 * 32];
  __shared__ alignas(16) short Ws[2 * 128 * 32];
  // XCD-chunked swizzle: nwg = 8*256 = 2048, chunk = 256. Same-bm blocks cluster.
  int lin = blockIdx.y * 8 + blockIdx.x;
  lin = (lin & 7) * 256 + (lin >> 3);
  const int bn = lin & 7;   // 0..7
  const int bm = lin >> 3;  // 0..255
  const int rowBase = bm * 128, colBase = bn * 128;

  f32x4 acc[4][4] = {};
  gemm_core_128<1024>(att + (size_t)rowBase * 1024, WoB + (size_t)colBase * 1024, As, Ws, acc);

  const int tid = threadIdx.x;
  const int lane = tid & 63;
  const int wm = (tid >> 6) & 1, wn = tid >> 7;
  const int l15 = lane & 15, quad = lane >> 4;
#pragma unroll
  for (int j = 0; j < 4; ++j) {
    const int gcol = colBase + wn * 64 + j * 16 + l15;
    const float bval = bo[gcol];
#pragma unroll
    for (int i = 0; i < 4; ++i) {
#pragma unroll
      for (int r = 0; r < 4; ++r) {
        int grow = rowBase + wm * 64 + i * 16 + quad * 4 + r;
        out[(size_t)grow * 1024 + gcol] = acc[i][j][r] + bval;
      }
    }
  }
}

extern "C" void kernel_launch(void* const* d_in, const int* in_sizes, int n_in,
                              void* d_out, int out_size, void* d_ws, size_t ws_size,
                              hipStream_t stream) {
  const float* x  = (const float*)d_in[0];
  const float* Wq = (const float*)d_in[1];
  const float* bq = (const float*)d_in[2];
  const float* Wk = (const float*)d_in[3];
  const float* bk = (const float*)d_in[4];
  const float* Wv = (const float*)d_in[5];
  const float* bv = (const float*)d_in[6];
  const float* Wo = (const float*)d_in[7];
  const float* bo = (const float*)d_in[8];
  float* out = (float*)d_out;

  char* ws = (char*)d_ws;
  short* h    = (short*)(ws);                 // 67,108,864 B (reused as att later)
  short* Wcat = (short*)(ws + 67108864);      //  8,388,608 B ([Wq;Wk;Wv;Wo] bf16)
  short* pq   = (short*)(ws + 75497472);      // 67,108,864 B
  short* pkT  = (short*)(ws + 142606336);     // 67,108,864 B
  short* vT   = (short*)(ws + 209715200);     // 67,108,864 B
  short* kvT  = (short*)(ws + 276824064);     //  4,194,304 B
  float* z    = (float*)(ws + 281018368);     //     65,536 B

  prep_h<<<16384, 256, 0, stream>>>(x, h);
  pack_w<<<4096, 256, 0, stream>>>(Wq, Wk, Wv, Wo, Wcat);
  gemm_qkv<<<dim3(24, 256), 256, 0, stream>>>(h, Wcat, bq, bk, bv, pq, pkT, vT);
  kv_kernel<<<128, 256, 0, stream>>>(pkT, vT, kvT, z);
  attn_kernel<<<dim3(16, 128), 256, 0, stream>>>(pq, kvT, z, h /* att reuses h */);
  gemm_out<<<dim3(8, 256), 256, 0, stream>>>(h, Wcat + 3145728, bo, out);
}

// Round 3
// 1089.654 us; speedup vs baseline: 1.0632x; 1.0632x over previous
//
#include <hip/hip_runtime.h>
#include <hip/hip_bf16.h>
#include <stdint.h>

// LMHA: linear multi-head attention (elu+1 feature map), S=2048 B=16 D=1024 H=8 dh=128
// Pipeline: prep_h -> pack_w -> gemm_qkv (fused bias+elu+scatter) -> kv_kernel (kv state + z)
//           -> attn_kernel (num, den, divide) -> gemm_out (+bo)
// R1: m97 128x128 core (global_load_lds w=16, linear LDS, 2 barriers/step): 344 TF, latency-bound.
// R2: FAILED: dbuf + 1-D XCD chunk -> W set (6MB) > per-XCD L2 (4MB) thrashed, FETCH up.
// R3: (a) 256x256 tile, 8 waves (2Mx4N), 512 thr for gemm_qkv/gemm_out: halves staged
//     bytes, 4x compute per K-step vs exposed latency. Same 2-barrier schedule.
//     (b) 2-D XCD partition: qkv XCD(xm,xn) owns 32bm x 6bn -> W/XCD = 3MB (L2-resident),
//     A panels stream bn-fast. gemm_out: Wo 2MB resident/XCD. kv/attn: natural order, 128^2 core.

typedef __bf16 bf16x8 __attribute__((ext_vector_type(8)));
typedef float f32x4 __attribute__((ext_vector_type(4)));

#define S_LEN 2048
#define B_SZ  16
#define D_MOD 1024
#define N_H   8
#define D_H   128

__device__ __forceinline__ short f2bf(float f) {
  __bf16 b = (__bf16)f;
  return __builtin_bit_cast(short, b);
}

// async global->LDS, 16B per lane. Dest must be wave-uniform base + lane*16.
__device__ __forceinline__ void gload_lds16(const short* g, short* l) {
  __builtin_amdgcn_global_load_lds(
      (__attribute__((address_space(1))) void*)(g),
      (__attribute__((address_space(3))) void*)(l), 16, 0, 0);
}

// ---------------- prep: h = bf16(x + pos_encoding) ----------------
__global__ void prep_h(const float* __restrict__ x, short* __restrict__ h) {
  size_t idx8 = (size_t)blockIdx.x * blockDim.x + threadIdx.x; // 8 elems / thread
  size_t base = idx8 * 8;                                      // < 33,554,432
  int d = (int)(base & 1023);
  int r = (int)(base >> 10);
  int s = r >> 4; // row = s*B + b
  float4 v0 = *(const float4*)(x + base);
  float4 v1 = *(const float4*)(x + base + 4);
  float vs[8] = {v0.x, v0.y, v0.z, v0.w, v1.x, v1.y, v1.z, v1.w};
  const float kdiv = -9.210340371976184f / 1024.0f; // -ln(10000)/D
  bf16x8 ov;
#pragma unroll
  for (int t = 0; t < 8; ++t) {
    int dc = d + t;
    float div = __expf((float)(dc & ~1) * kdiv);
    float ang = (float)s * div;
    float pe = (dc & 1) ? __cosf(ang) : __sinf(ang);
    ov[t] = (__bf16)(vs[t] + pe);
  }
  *(bf16x8*)(h + base) = ov;
}

// ---------------- pack weights to bf16: [Wq;Wk;Wv;Wo] = [4096,1024] ----------------
__global__ void pack_w(const float* __restrict__ Wq, const float* __restrict__ Wk,
                       const float* __restrict__ Wv, const float* __restrict__ Wo,
                       short* __restrict__ Wcat) {
  size_t i4 = (size_t)blockIdx.x * blockDim.x + threadIdx.x;
  size_t base = i4 * 4; // < 4,194,304
  const float* src;
  size_t off;
  if (base < 1048576)      { src = Wq; off = base; }
  else if (base < 2097152) { src = Wk; off = base - 1048576; }
  else if (base < 3145728) { src = Wv; off = base - 2097152; }
  else                     { src = Wo; off = base - 3145728; }
  float4 v = *(const float4*)(src + off);
  alignas(8) short o[4] = {f2bf(v.x), f2bf(v.y), f2bf(v.z), f2bf(v.w)};
  *(uint2*)(Wcat + base) = *(const uint2*)o;
}

// ---------------- GEMM core A: 128x128 tile, 256 thr, 4 waves (2x2), m97 2-barrier ----
template <int K>
__device__ __forceinline__ void gemm_core_128(const short* __restrict__ A,
                                              const short* __restrict__ W,
                                              short* As, short* Ws,
                                              f32x4 (&acc)[4][4]) {
  const int tid = threadIdx.x;
  const int c8 = tid & 3, r0 = tid >> 2; // stage: row r0 (0..63), col c8*8
  const int lane = tid & 63;
  const int wm = (tid >> 6) & 1, wn = tid >> 7;
  const int l15 = lane & 15, quad = lane >> 4;

  const short* ga0 = A + (size_t)r0 * K + c8 * 8;
  const short* ga1 = ga0 + (size_t)64 * K;
  const short* gw0 = W + (size_t)r0 * K + c8 * 8;
  const short* gw1 = gw0 + (size_t)64 * K;
  short* la0 = As + r0 * 32 + c8 * 8;
  short* la1 = la0 + 64 * 32;
  short* lw0 = Ws + r0 * 32 + c8 * 8;
  short* lw1 = lw0 + 64 * 32;

  for (int k0 = 0; k0 < K; k0 += 32) {
    __syncthreads();
    gload_lds16(ga0 + k0, la0);
    gload_lds16(ga1 + k0, la1);
    gload_lds16(gw0 + k0, lw0);
    gload_lds16(gw1 + k0, lw1);
    __syncthreads();
    bf16x8 af[4], wf[4];
#pragma unroll
    for (int i = 0; i < 4; ++i)
      af[i] = *(const bf16x8*)&As[(wm * 64 + i * 16 + l15) * 32 + quad * 8];
#pragma unroll
    for (int j = 0; j < 4; ++j)
      wf[j] = *(const bf16x8*)&Ws[(wn * 64 + j * 16 + l15) * 32 + quad * 8];
#pragma unroll
    for (int i = 0; i < 4; ++i)
#pragma unroll
      for (int j = 0; j < 4; ++j)
        acc[i][j] = __builtin_amdgcn_mfma_f32_16x16x32_bf16(af[i], wf[j], acc[i][j], 0, 0, 0);
  }
}

// ---------------- GEMM core B: 256x256 tile, 512 thr, 8 waves (2M x 4N) --------------
// Per-wave output 128x64 (acc[8][4]). LDS: As/Ws [256][32] shorts (16KB each).
// Per BK=32 step: 4x global_load_lds_dwordx4 per thread-group, 2 barriers,
// 12 ds_read_b128 + 32 MFMA per wave.
template <int K>
__device__ __forceinline__ void gemm_core_256(const short* __restrict__ A,
                                              const short* __restrict__ W,
                                              short* As, short* Ws,
                                              f32x4 (&acc)[8][4]) {
  const int tid = threadIdx.x;           // 0..511
  const int c8 = tid & 3, r0 = tid >> 2; // stage row 0..127, col c8*8
  const int lane = tid & 63;
  const int wave = tid >> 6;             // 0..7
  const int wm = wave & 1;               // M half base wm*128
  const int wn = wave >> 1;              // N quarter base wn*64
  const int l15 = lane & 15, quad = lane >> 4;

  const short* ga0 = A + (size_t)r0 * K + c8 * 8;
  const short* ga1 = ga0 + (size_t)128 * K;
  const short* gw0 = W + (size_t)r0 * K + c8 * 8;
  const short* gw1 = gw0 + (size_t)128 * K;
  short* la0 = As + r0 * 32 + c8 * 8; // byte off = tid*16: wave-uniform + lane*16
  short* la1 = la0 + 128 * 32;
  short* lw0 = Ws + r0 * 32 + c8 * 8;
  short* lw1 = lw0 + 128 * 32;

  for (int k0 = 0; k0 < K; k0 += 32) {
    __syncthreads();
    gload_lds16(ga0 + k0, la0);
    gload_lds16(ga1 + k0, la1);
    gload_lds16(gw0 + k0, lw0);
    gload_lds16(gw1 + k0, lw1);
    __syncthreads();
    bf16x8 af[8], wf[4];
#pragma unroll
    for (int i = 0; i < 8; ++i)
      af[i] = *(const bf16x8*)&As[(wm * 128 + i * 16 + l15) * 32 + quad * 8];
#pragma unroll
    for (int j = 0; j < 4; ++j)
      wf[j] = *(const bf16x8*)&Ws[(wn * 64 + j * 16 + l15) * 32 + quad * 8];
#pragma unroll
    for (int i = 0; i < 8; ++i)
#pragma unroll
      for (int j = 0; j < 4; ++j)
        acc[i][j] = __builtin_amdgcn_mfma_f32_16x16x32_bf16(af[i], wf[j], acc[i][j], 0, 0, 0);
  }
}

// ---------------- GEMM1: qkv = h @ Wqkv^T, fused bias + elu+1, scatter ----------------
// 256x256 tiles: grid (12 bn, 128 bm). 2-D XCD partition: XCD(xm=x>>1, xn=x&1) owns
// bm in [xm*32,+32) x bn in [xn*6,+6); within-XCD order bn-fast -> A panel hot across
// its 6 uses, W working set 6*512KB = 3MB L2-resident.
__launch_bounds__(512, 2)
__global__ void gemm_qkv(const short* __restrict__ h, const short* __restrict__ Wqkv,
                         const float* __restrict__ bq, const float* __restrict__ bk,
                         const float* __restrict__ bv,
                         short* __restrict__ pq, short* __restrict__ pkT,
                         short* __restrict__ vT) {
  __shared__ alignas(16) short As[256 * 32];
  __shared__ alignas(16) short Ws[256 * 32];
  const int lin = blockIdx.y * 12 + blockIdx.x; // 0..1535
  const int x = lin & 7, q = lin >> 3;          // q 0..191
  const int xm = x >> 1, xn = x & 1;
  const int bm = xm * 32 + q / 6;               // 0..127
  const int bn = xn * 6 + q % 6;                // 0..11
  const int rowBase = bm * 256, colBase = bn * 256;

  f32x4 acc[8][4] = {};
  gemm_core_256<1024>(h + (size_t)rowBase * 1024, Wqkv + (size_t)colBase * 1024, As, Ws, acc);

  const int tid = threadIdx.x;
  const int lane = tid & 63;
  const int wave = tid >> 6;
  const int wm = wave & 1, wn = wave >> 1;
  const int l15 = lane & 15, quad = lane >> 4;

  const int p = colBase >> 10; // 0:q 1:k 2:v (uniform: 256 | 1024)
  const float* bias = (p == 0) ? bq : (p == 1) ? bk : bv;

#pragma unroll
  for (int j = 0; j < 4; ++j) {
    const int cglob = colBase + wn * 64 + j * 16 + l15; // global col in [0,3072)
    const int hh = (cglob >> 7) & 7;
    const int e = cglob & 127;
    const float bval = bias[cglob & 1023];
#pragma unroll
    for (int i = 0; i < 8; ++i) {
#pragma unroll
      for (int r = 0; r < 4; ++r) {
        int grow = rowBase + wm * 128 + i * 16 + quad * 4 + r;
        int s = grow >> 4, b = grow & 15;
        float v = acc[i][j][r] + bval;
        if (p == 0) {
          float u = v > 0.f ? v + 1.f : __expf(v); // elu(v)+1
          pq[(((size_t)b * N_H + hh) * S_LEN + s) * D_H + e] = f2bf(u);
        } else if (p == 1) {
          float u = v > 0.f ? v + 1.f : __expf(v);
          pkT[(((size_t)b * N_H + hh) * D_H + e) * S_LEN + s] = f2bf(u);
        } else {
          vT[(((size_t)b * N_H + hh) * D_H + e) * S_LEN + s] = f2bf(v);
        }
      }
    }
  }
}

// ---------------- kv state: kvT[bh][e][d] = sum_s vT[e][s]*pkT[d][s]; z[bh][d] ----------------
__launch_bounds__(256)
__global__ void kv_kernel(const short* __restrict__ pkT, const short* __restrict__ vT,
                          short* __restrict__ kvT, float* __restrict__ z) {
  __shared__ alignas(16) short As[128 * 32];
  __shared__ alignas(16) short Ws[128 * 32];
  const int bh = blockIdx.x; // 0..127
  const short* Abase = vT + (size_t)bh * D_H * S_LEN;  // rows = e
  const short* Wbase = pkT + (size_t)bh * D_H * S_LEN; // rows = d

  f32x4 acc[4][4] = {};
  gemm_core_128<2048>(Abase, Wbase, As, Ws, acc);

  const int tid = threadIdx.x;
  const int lane = tid & 63;
  const int wm = (tid >> 6) & 1, wn = tid >> 7;
  const int l15 = lane & 15, quad = lane >> 4;

#pragma unroll
  for (int j = 0; j < 4; ++j) {
    const int d = wn * 64 + j * 16 + l15;
#pragma unroll
    for (int i = 0; i < 4; ++i) {
#pragma unroll
      for (int r = 0; r < 4; ++r) {
        int e = wm * 64 + i * 16 + quad * 4 + r;
        kvT[(size_t)bh * (D_H * D_H) + (size_t)e * D_H + d] = f2bf(acc[i][j][r]);
      }
    }
  }
  // z[d] = sum_s pk[d][s]  (re-read pkT rows, L2-hot)
  __syncthreads();
  if (tid < 128) {
    const short* prow = Wbase + (size_t)tid * S_LEN;
    float sum = 0.f;
    for (int s = 0; s < S_LEN; s += 8) {
      bf16x8 vv = *(const bf16x8*)(prow + s);
#pragma unroll
      for (int t = 0; t < 8; ++t) sum += (float)vv[t];
    }
    z[bh * D_H + tid] = sum;
  }
}

// ---------------- num/den/divide: att = (pq @ kv) / (pq . z + eps) ----------------
__launch_bounds__(256)
__global__ void attn_kernel(const short* __restrict__ pq, const short* __restrict__ kvT,
                            const float* __restrict__ z, short* __restrict__ att) {
  __shared__ alignas(16) short As[128 * 32];
  __shared__ alignas(16) short Ws[128 * 32];
  __shared__ float den_lds[128];
  __shared__ float z_lds[128];
  const int s0 = blockIdx.x * 128; // 16 tiles over S
  const int bh = blockIdx.y;       // 0..127
  const int tid = threadIdx.x;
  if (tid < 128) z_lds[tid] = z[bh * D_H + tid];

  const short* Abase = pq + ((size_t)bh * S_LEN + s0) * D_H; // rows = s
  const short* Wbase = kvT + (size_t)bh * (D_H * D_H);       // rows = e, cols = d

  f32x4 acc[4][4] = {};
  gemm_core_128<128>(Abase, Wbase, As, Ws, acc);

  // den[s] = sum_d pq[s][d] * z[d] + eps
  __syncthreads();
  if (tid < 128) {
    const short* prow = Abase + (size_t)tid * D_H;
    float sum = 0.f;
#pragma unroll
    for (int d = 0; d < D_H; d += 8) {
      bf16x8 vv = *(const bf16x8*)(prow + d);
#pragma unroll
      for (int t = 0; t < 8; ++t) sum += (float)vv[t] * z_lds[d + t];
    }
    den_lds[tid] = sum + 1e-6f;
  }
  __syncthreads();

  const int lane = tid & 63;
  const int wm = (tid >> 6) & 1, wn = tid >> 7;
  const int l15 = lane & 15, quad = lane >> 4;
  const int b = bh >> 3, hd = bh & 7;
#pragma unroll
  for (int j = 0; j < 4; ++j) {
    const int e = wn * 64 + j * 16 + l15;
#pragma unroll
    for (int i = 0; i < 4; ++i) {
#pragma unroll
      for (int r = 0; r < 4; ++r) {
        int mloc = wm * 64 + i * 16 + quad * 4 + r; // s_local
        float a = acc[i][j][r] / den_lds[mloc];
        att[((size_t)(s0 + mloc) * B_SZ + b) * D_MOD + hd * D_H + e] = f2bf(a);
      }
    }
  }
}

// ---------------- out = att @ Wo^T + bo (fp32 out), 256x256 tiles ----------------
// grid (4 bn, 128 bm). XCD x owns bm in [x*16,+16), all 4 bn (Wo 2MB L2-resident),
// bn-fast order.
__launch_bounds__(512, 2)
__global__ void gemm_out(const short* __restrict__ att, const short* __restrict__ WoB,
                         const float* __restrict__ bo, float* __restrict__ out) {
  __shared__ alignas(16) short As[256 * 32];
  __shared__ alignas(16) short Ws[256 * 32];
  const int lin = blockIdx.y * 4 + blockIdx.x; // 0..511
  const int x = lin & 7, q = lin >> 3;         // q 0..63
  const int bn = q & 3;                        // 0..3
  const int bm = x * 16 + (q >> 2);            // 0..127
  const int rowBase = bm * 256, colBase = bn * 256;

  f32x4 acc[8][4] = {};
  gemm_core_256<1024>(att + (size_t)rowBase * 1024, WoB + (size_t)colBase * 1024, As, Ws, acc);

  const int tid = threadIdx.x;
  const int lane = tid & 63;
  const int wave = tid >> 6;
  const int wm = wave & 1, wn = wave >> 1;
  const int l15 = lane & 15, quad = lane >> 4;
#pragma unroll
  for (int j = 0; j < 4; ++j) {
    const int gcol = colBase + wn * 64 + j * 16 + l15;
    const float bval = bo[gcol];
#pragma unroll
    for (int i = 0; i < 8; ++i) {
#pragma unroll
      for (int r = 0; r < 4; ++r) {
        int grow = rowBase + wm * 128 + i * 16 + quad * 4 + r;
        out[(size_t)grow * 1024 + gcol] = acc[i][j][r] + bval;
      }
    }
  }
}

extern "C" void kernel_launch(void* const* d_in, const int* in_sizes, int n_in,
                              void* d_out, int out_size, void* d_ws, size_t ws_size,
                              hipStream_t stream) {
  const float* x  = (const float*)d_in[0];
  const float* Wq = (const float*)d_in[1];
  const float* bq = (const float*)d_in[2];
  const float* Wk = (const float*)d_in[3];
  const float* bk = (const float*)d_in[4];
  const float* Wv = (const float*)d_in[5];
  const float* bv = (const float*)d_in[6];
  const float* Wo = (const float*)d_in[7];
  const float* bo = (const float*)d_in[8];
  float* out = (float*)d_out;

  char* ws = (char*)d_ws;
  short* h    = (short*)(ws);                 // 67,108,864 B (reused as att later)
  short* Wcat = (short*)(ws + 67108864);      //  8,388,608 B ([Wq;Wk;Wv;Wo] bf16)
  short* pq   = (short*)(ws + 75497472);      // 67,108,864 B
  short* pkT  = (short*)(ws + 142606336);     // 67,108,864 B
  short* vT   = (short*)(ws + 209715200);     // 67,108,864 B
  short* kvT  = (short*)(ws + 276824064);     //  4,194,304 B
  float* z    = (float*)(ws + 281018368);     //     65,536 B

  prep_h<<<16384, 256, 0, stream>>>(x, h);
  pack_w<<<4096, 256, 0, stream>>>(Wq, Wk, Wv, Wo, Wcat);
  gemm_qkv<<<dim3(12, 128), 512, 0, stream>>>(h, Wcat, bq, bk, bv, pq, pkT, vT);
  kv_kernel<<<128, 256, 0, stream>>>(pkT, vT, kvT, z);
  attn_kernel<<<dim3(16, 128), 256, 0, stream>>>(pq, kvT, z, h /* att reuses h */);
  gemm_out<<<dim3(4, 128), 512, 0, stream>>>(h, Wcat + 3145728, bo, out);
}

// Round 4
// 992.415 us; speedup vs baseline: 1.1673x; 1.0980x over previous
//
#include <hip/hip_runtime.h>
#include <hip/hip_bf16.h>
#include <stdint.h>

// LMHA: linear multi-head attention (elu+1 feature map), S=2048 B=16 D=1024 H=8 dh=128
// Pipeline: prep_h -> pack_w -> gemm_qkv (fused bias+elu+scatter) -> kv_kernel (kv state + z)
//           -> attn_kernel (num, den, divide) -> gemm_out (+bo)
// R1: m97 128x128 core (global_load_lds w=16, linear LDS, 2 barriers/step): latency-bound, 14%.
// R2: FAILED: dbuf + 1-D XCD chunk -> W set (6MB) > per-XCD L2 (4MB) thrashed.
// R3: 256x256 tile + 2-D XCD partition: FETCH 580->232MB (locality fixed) but MfmaUtil
//     still 12.8% -> the 2-barrier vmcnt(0)-drain schedule is the bottleneck (m233).
// R4: depth-3 counted-vmcnt pipeline (T3+T4): 4 LDS buffers, ONE raw s_barrier per
//     K-tile, s_waitcnt vmcnt(8/4/0) counted (never 0 in main loop), loads span
//     barriers. T2 XOR swizzle (byte ^= ((byte>>7)&3)<<4) on stage-source + reads
//     (linear gload_lds dest per rule #21). T5 setprio around MFMA cluster.
//     Trailing lgkmcnt(0)+sched_barrier(0) per iter fences read-vs-overwrite (rule #18).

typedef __bf16 bf16x8 __attribute__((ext_vector_type(8)));
typedef float f32x4 __attribute__((ext_vector_type(4)));

#define S_LEN 2048
#define B_SZ  16
#define D_MOD 1024
#define N_H   8
#define D_H   128

__device__ __forceinline__ short f2bf(float f) {
  __bf16 b = (__bf16)f;
  return __builtin_bit_cast(short, b);
}

// async global->LDS, 16B per lane. Dest must be wave-uniform base + lane*16 (linear).
__device__ __forceinline__ void gload_lds16(const short* g, short* l) {
  __builtin_amdgcn_global_load_lds(
      (__attribute__((address_space(1))) void*)(g),
      (__attribute__((address_space(3))) void*)(l), 16, 0, 0);
}

// LDS bank swizzle for 64B rows: XOR byte bits 4-5 with bits 7-8 (row bits 1-2).
// Involution (selector bits disjoint from target bits), preserves 16B alignment.
// Frag read (16 lanes, same 16B col-slot, consecutive rows): banks spread over all
// 8 bank-quads, 2 lanes each -> conflict-free (2-way is free, m136).
__device__ __forceinline__ int swz(int o) { return o ^ (((o >> 7) & 3) << 4); }

// ---------------- prep: h = bf16(x + pos_encoding) ----------------
__global__ void prep_h(const float* __restrict__ x, short* __restrict__ h) {
  size_t idx8 = (size_t)blockIdx.x * blockDim.x + threadIdx.x; // 8 elems / thread
  size_t base = idx8 * 8;                                      // < 33,554,432
  int d = (int)(base & 1023);
  int r = (int)(base >> 10);
  int s = r >> 4; // row = s*B + b
  float4 v0 = *(const float4*)(x + base);
  float4 v1 = *(const float4*)(x + base + 4);
  float vs[8] = {v0.x, v0.y, v0.z, v0.w, v1.x, v1.y, v1.z, v1.w};
  const float kdiv = -9.210340371976184f / 1024.0f; // -ln(10000)/D
  bf16x8 ov;
#pragma unroll
  for (int t = 0; t < 8; ++t) {
    int dc = d + t;
    float div = __expf((float)(dc & ~1) * kdiv);
    float ang = (float)s * div;
    float pe = (dc & 1) ? __cosf(ang) : __sinf(ang);
    ov[t] = (__bf16)(vs[t] + pe);
  }
  *(bf16x8*)(h + base) = ov;
}

// ---------------- pack weights to bf16: [Wq;Wk;Wv;Wo] = [4096,1024] ----------------
__global__ void pack_w(const float* __restrict__ Wq, const float* __restrict__ Wk,
                       const float* __restrict__ Wv, const float* __restrict__ Wo,
                       short* __restrict__ Wcat) {
  size_t i4 = (size_t)blockIdx.x * blockDim.x + threadIdx.x;
  size_t base = i4 * 4; // < 4,194,304
  const float* src;
  size_t off;
  if (base < 1048576)      { src = Wq; off = base; }
  else if (base < 2097152) { src = Wk; off = base - 1048576; }
  else if (base < 3145728) { src = Wv; off = base - 2097152; }
  else                     { src = Wo; off = base - 3145728; }
  float4 v = *(const float4*)(src + off);
  alignas(8) short o[4] = {f2bf(v.x), f2bf(v.y), f2bf(v.z), f2bf(v.w)};
  *(uint2*)(Wcat + base) = *(const uint2*)o;
}

// ================= pipelined GEMM core, 256x256 tile, 512 thr, 8 waves (2M x 4N) ====
// bt-form C[m][n] = sum_k A[m][k]*W[n][k]. K-tile BK=32. LDS: 4 buffers x
// (A 16KB + B 16KB) = 128KB. Depth-3 pipeline: tiles t..t+2 in flight; stage of
// tile t+3 targets buf[(t-1)&3] (reads of it finished before this iter's barrier).
// Per iter: vmcnt(8) [own tile-t loads done] -> s_barrier [all waves' done; prev
// reads done] -> ds_read 12 frags -> issue 4 gload_lds (t+3) -> setprio+32 MFMA ->
// lgkmcnt(0)+sched_barrier (all reads complete before next barrier).
template <int K>
__device__ __forceinline__ void core_256(const short* __restrict__ A,
                                         const short* __restrict__ W,
                                         char* Lb, f32x4 (&acc)[8][4]) {
  constexpr int NT = K / 32;
  static_assert(NT >= 4, "pipeline needs K >= 128");
  const int tid = threadIdx.x;
  const int lane = tid & 63;
  const int wave = tid >> 6;
  const int wm = wave & 1, wn = wave >> 1;
  const int l15 = lane & 15, quad = lane >> 4;

  // stage: linear LDS dest o = chunk*8192 + tid*16; global source pre-swizzled so
  // LDS[o] = tileElem(swz(o)) -> reads at swz(logical) recover tileElem(logical).
  const int oA0 = tid * 16, oA1 = 8192 + tid * 16;
  const int lA0 = swz(oA0), lA1 = swz(oA1);
  const short* gA0 = A + (size_t)(lA0 >> 6) * K + ((lA0 & 63) >> 1);
  const short* gA1 = A + (size_t)((lA1 - 8192) >> 6) * K + 128 * K + (((lA1 - 8192) & 63) >> 1);
  const short* gW0 = W + (size_t)(lA0 >> 6) * K + ((lA0 & 63) >> 1);
  const short* gW1 = W + (size_t)((lA1 - 8192) >> 6) * K + 128 * K + (((lA1 - 8192) & 63) >> 1);

  int rA[8], rW[4];
#pragma unroll
  for (int i = 0; i < 8; ++i)
    rA[i] = swz((wm * 128 + i * 16 + l15) * 64 + quad * 16);
#pragma unroll
  for (int j = 0; j < 4; ++j)
    rW[j] = 16384 + swz((wn * 64 + j * 16 + l15) * 64 + quad * 16);

  auto stage = [&](int t) {
    char* sb = Lb + (t & 3) * 32768;
    const int k0 = t * 32;
    gload_lds16(gA0 + k0, (short*)(sb + oA0));
    gload_lds16(gA1 + k0, (short*)(sb + oA1));
    gload_lds16(gW0 + k0, (short*)(sb + 16384 + oA0));
    gload_lds16(gW1 + k0, (short*)(sb + 16384 + oA1));
  };
  auto step = [&](int t, bool do_stage) {
    char* cb = Lb + (t & 3) * 32768;
    bf16x8 af[8], wf[4];
#pragma unroll
    for (int i = 0; i < 8; ++i) af[i] = *(const bf16x8*)(cb + rA[i]);
#pragma unroll
    for (int j = 0; j < 4; ++j) wf[j] = *(const bf16x8*)(cb + rW[j]);
    if (do_stage) stage(t + 3);
    __builtin_amdgcn_s_setprio(1);
#pragma unroll
    for (int i = 0; i < 8; ++i)
#pragma unroll
      for (int j = 0; j < 4; ++j)
        acc[i][j] = __builtin_amdgcn_mfma_f32_16x16x32_bf16(af[i], wf[j], acc[i][j], 0, 0, 0);
    __builtin_amdgcn_s_setprio(0);
    // all my LDS reads complete before I can reach the next barrier -> safe for
    // other waves to overwrite this buffer after that barrier.
    asm volatile("s_waitcnt lgkmcnt(0)" ::: "memory");
    __builtin_amdgcn_sched_barrier(0);
  };

  stage(0); stage(1); stage(2); // 12 loads in flight

  for (int t = 0; t <= NT - 4; ++t) {
    asm volatile("s_waitcnt vmcnt(8)" ::: "memory"); // my tile-t loads landed
    __builtin_amdgcn_s_barrier();                    // everyone's landed
    step(t, true);
  }
  asm volatile("s_waitcnt vmcnt(8)" ::: "memory");
  __builtin_amdgcn_s_barrier();
  step(NT - 3, false);
  asm volatile("s_waitcnt vmcnt(4)" ::: "memory");
  __builtin_amdgcn_s_barrier();
  step(NT - 2, false);
  asm volatile("s_waitcnt vmcnt(0)" ::: "memory");
  __builtin_amdgcn_s_barrier();
  step(NT - 1, false);
}

// ================= pipelined GEMM core, 128x128 tile, 256 thr, 4 waves (2x2) ========
// Same schedule; LDS: 4 buffers x (A 8KB + B 8KB) = 64KB.
template <int K>
__device__ __forceinline__ void core_128(const short* __restrict__ A,
                                         const short* __restrict__ W,
                                         char* Lb, f32x4 (&acc)[4][4]) {
  constexpr int NT = K / 32;
  static_assert(NT >= 4, "pipeline needs K >= 128");
  const int tid = threadIdx.x;
  const int lane = tid & 63;
  const int wm = (tid >> 6) & 1, wn = tid >> 7;
  const int l15 = lane & 15, quad = lane >> 4;

  const int oA0 = tid * 16, oA1 = 4096 + tid * 16;
  const int lA0 = swz(oA0), lA1 = swz(oA1);
  const short* gA0 = A + (size_t)(lA0 >> 6) * K + ((lA0 & 63) >> 1);
  const short* gA1 = A + (size_t)((lA1 - 4096) >> 6) * K + 64 * K + (((lA1 - 4096) & 63) >> 1);
  const short* gW0 = W + (size_t)(lA0 >> 6) * K + ((lA0 & 63) >> 1);
  const short* gW1 = W + (size_t)((lA1 - 4096) >> 6) * K + 64 * K + (((lA1 - 4096) & 63) >> 1);

  int rA[4], rW[4];
#pragma unroll
  for (int i = 0; i < 4; ++i)
    rA[i] = swz((wm * 64 + i * 16 + l15) * 64 + quad * 16);
#pragma unroll
  for (int j = 0; j < 4; ++j)
    rW[j] = 8192 + swz((wn * 64 + j * 16 + l15) * 64 + quad * 16);

  auto stage = [&](int t) {
    char* sb = Lb + (t & 3) * 16384;
    const int k0 = t * 32;
    gload_lds16(gA0 + k0, (short*)(sb + oA0));
    gload_lds16(gA1 + k0, (short*)(sb + oA1));
    gload_lds16(gW0 + k0, (short*)(sb + 8192 + oA0));
    gload_lds16(gW1 + k0, (short*)(sb + 8192 + oA1));
  };
  auto step = [&](int t, bool do_stage) {
    char* cb = Lb + (t & 3) * 16384;
    bf16x8 af[4], wf[4];
#pragma unroll
    for (int i = 0; i < 4; ++i) af[i] = *(const bf16x8*)(cb + rA[i]);
#pragma unroll
    for (int j = 0; j < 4; ++j) wf[j] = *(const bf16x8*)(cb + rW[j]);
    if (do_stage) stage(t + 3);
    __builtin_amdgcn_s_setprio(1);
#pragma unroll
    for (int i = 0; i < 4; ++i)
#pragma unroll
      for (int j = 0; j < 4; ++j)
        acc[i][j] = __builtin_amdgcn_mfma_f32_16x16x32_bf16(af[i], wf[j], acc[i][j], 0, 0, 0);
    __builtin_amdgcn_s_setprio(0);
    asm volatile("s_waitcnt lgkmcnt(0)" ::: "memory");
    __builtin_amdgcn_sched_barrier(0);
  };

  stage(0); stage(1); stage(2);

  for (int t = 0; t <= NT - 4; ++t) {
    asm volatile("s_waitcnt vmcnt(8)" ::: "memory");
    __builtin_amdgcn_s_barrier();
    step(t, true);
  }
  asm volatile("s_waitcnt vmcnt(8)" ::: "memory");
  __builtin_amdgcn_s_barrier();
  step(NT - 3, false);
  asm volatile("s_waitcnt vmcnt(4)" ::: "memory");
  __builtin_amdgcn_s_barrier();
  step(NT - 2, false);
  asm volatile("s_waitcnt vmcnt(0)" ::: "memory");
  __builtin_amdgcn_s_barrier();
  step(NT - 1, false);
}

// ---------------- GEMM1: qkv = h @ Wqkv^T, fused bias + elu+1, scatter ----------------
// 256x256 tiles: grid (12 bn, 128 bm). 2-D XCD partition (kept from R3, FETCH-verified):
// XCD(xm=x>>1, xn=x&1) owns bm in [xm*32,+32) x bn in [xn*6,+6), bn-fast.
__launch_bounds__(512, 2)
__global__ void gemm_qkv(const short* __restrict__ h, const short* __restrict__ Wqkv,
                         const float* __restrict__ bq, const float* __restrict__ bk,
                         const float* __restrict__ bv,
                         short* __restrict__ pq, short* __restrict__ pkT,
                         short* __restrict__ vT) {
  __shared__ alignas(16) char Lb[131072];
  const int lin = blockIdx.y * 12 + blockIdx.x; // 0..1535
  const int x = lin & 7, q = lin >> 3;          // q 0..191
  const int xm = x >> 1, xn = x & 1;
  const int bm = xm * 32 + q / 6;               // 0..127
  const int bn = xn * 6 + q % 6;                // 0..11
  const int rowBase = bm * 256, colBase = bn * 256;

  f32x4 acc[8][4] = {};
  core_256<1024>(h + (size_t)rowBase * 1024, Wqkv + (size_t)colBase * 1024, Lb, acc);

  const int tid = threadIdx.x;
  const int lane = tid & 63;
  const int wave = tid >> 6;
  const int wm = wave & 1, wn = wave >> 1;
  const int l15 = lane & 15, quad = lane >> 4;

  const int p = colBase >> 10; // 0:q 1:k 2:v (uniform: 256 | 1024)
  const float* bias = (p == 0) ? bq : (p == 1) ? bk : bv;

#pragma unroll
  for (int j = 0; j < 4; ++j) {
    const int cglob = colBase + wn * 64 + j * 16 + l15; // global col in [0,3072)
    const int hh = (cglob >> 7) & 7;
    const int e = cglob & 127;
    const float bval = bias[cglob & 1023];
#pragma unroll
    for (int i = 0; i < 8; ++i) {
#pragma unroll
      for (int r = 0; r < 4; ++r) {
        int grow = rowBase + wm * 128 + i * 16 + quad * 4 + r;
        int s = grow >> 4, b = grow & 15;
        float v = acc[i][j][r] + bval;
        if (p == 0) {
          float u = v > 0.f ? v + 1.f : __expf(v); // elu(v)+1
          pq[(((size_t)b * N_H + hh) * S_LEN + s) * D_H + e] = f2bf(u);
        } else if (p == 1) {
          float u = v > 0.f ? v + 1.f : __expf(v);
          pkT[(((size_t)b * N_H + hh) * D_H + e) * S_LEN + s] = f2bf(u);
        } else {
          vT[(((size_t)b * N_H + hh) * D_H + e) * S_LEN + s] = f2bf(v);
        }
      }
    }
  }
}

// ---------------- kv state: kvT[bh][e][d] = sum_s vT[e][s]*pkT[d][s]; z[bh][d] ----------------
__launch_bounds__(256, 2)
__global__ void kv_kernel(const short* __restrict__ pkT, const short* __restrict__ vT,
                          short* __restrict__ kvT, float* __restrict__ z) {
  __shared__ alignas(16) char Lb[65536];
  const int bh = blockIdx.x; // 0..127
  const short* Abase = vT + (size_t)bh * D_H * S_LEN;  // rows = e
  const short* Wbase = pkT + (size_t)bh * D_H * S_LEN; // rows = d

  f32x4 acc[4][4] = {};
  core_128<2048>(Abase, Wbase, Lb, acc);

  const int tid = threadIdx.x;
  const int lane = tid & 63;
  const int wm = (tid >> 6) & 1, wn = tid >> 7;
  const int l15 = lane & 15, quad = lane >> 4;

#pragma unroll
  for (int j = 0; j < 4; ++j) {
    const int d = wn * 64 + j * 16 + l15;
#pragma unroll
    for (int i = 0; i < 4; ++i) {
#pragma unroll
      for (int r = 0; r < 4; ++r) {
        int e = wm * 64 + i * 16 + quad * 4 + r;
        kvT[(size_t)bh * (D_H * D_H) + (size_t)e * D_H + d] = f2bf(acc[i][j][r]);
      }
    }
  }
  // z[d] = sum_s pk[d][s]  (re-read pkT rows, L2-hot)
  if (tid < 128) {
    const short* prow = Wbase + (size_t)tid * S_LEN;
    float sum = 0.f;
    for (int s = 0; s < S_LEN; s += 8) {
      bf16x8 vv = *(const bf16x8*)(prow + s);
#pragma unroll
      for (int t = 0; t < 8; ++t) sum += (float)vv[t];
    }
    z[bh * D_H + tid] = sum;
  }
}

// ---------------- num/den/divide: att = (pq @ kv) / (pq . z + eps) ----------------
__launch_bounds__(256, 2)
__global__ void attn_kernel(const short* __restrict__ pq, const short* __restrict__ kvT,
                            const float* __restrict__ z, short* __restrict__ att) {
  __shared__ alignas(16) char Lb[65536];
  __shared__ float den_lds[128];
  __shared__ float z_lds[128];
  const int s0 = blockIdx.x * 128; // 16 tiles over S
  const int bh = blockIdx.y;       // 0..127
  const int tid = threadIdx.x;

  const short* Abase = pq + ((size_t)bh * S_LEN + s0) * D_H; // rows = s
  const short* Wbase = kvT + (size_t)bh * (D_H * D_H);       // rows = e, cols = d

  f32x4 acc[4][4] = {};
  core_128<128>(Abase, Wbase, Lb, acc);

  // z load AFTER core (keeps core's vmcnt counting free of stray vmem ops)
  if (tid < 128) z_lds[tid] = z[bh * D_H + tid];
  __syncthreads();
  // den[s] = sum_d pq[s][d] * z[d] + eps
  if (tid < 128) {
    const short* prow = Abase + (size_t)tid * D_H;
    float sum = 0.f;
#pragma unroll
    for (int d = 0; d < D_H; d += 8) {
      bf16x8 vv = *(const bf16x8*)(prow + d);
#pragma unroll
      for (int t = 0; t < 8; ++t) sum += (float)vv[t] * z_lds[d + t];
    }
    den_lds[tid] = sum + 1e-6f;
  }
  __syncthreads();

  const int lane = tid & 63;
  const int wm = (tid >> 6) & 1, wn = tid >> 7;
  const int l15 = lane & 15, quad = lane >> 4;
  const int b = bh >> 3, hd = bh & 7;
#pragma unroll
  for (int j = 0; j < 4; ++j) {
    const int e = wn * 64 + j * 16 + l15;
#pragma unroll
    for (int i = 0; i < 4; ++i) {
#pragma unroll
      for (int r = 0; r < 4; ++r) {
        int mloc = wm * 64 + i * 16 + quad * 4 + r; // s_local
        float a = acc[i][j][r] / den_lds[mloc];
        att[((size_t)(s0 + mloc) * B_SZ + b) * D_MOD + hd * D_H + e] = f2bf(a);
      }
    }
  }
}

// ---------------- out = att @ Wo^T + bo (fp32 out), 256x256 tiles ----------------
// grid (4 bn, 128 bm). XCD x owns bm in [x*16,+16), all 4 bn (Wo 2MB L2-resident).
__launch_bounds__(512, 2)
__global__ void gemm_out(const short* __restrict__ att, const short* __restrict__ WoB,
                         const float* __restrict__ bo, float* __restrict__ out) {
  __shared__ alignas(16) char Lb[131072];
  const int lin = blockIdx.y * 4 + blockIdx.x; // 0..511
  const int x = lin & 7, q = lin >> 3;         // q 0..63
  const int bn = q & 3;                        // 0..3
  const int bm = x * 16 + (q >> 2);            // 0..127
  const int rowBase = bm * 256, colBase = bn * 256;

  f32x4 acc[8][4] = {};
  core_256<1024>(att + (size_t)rowBase * 1024, WoB + (size_t)colBase * 1024, Lb, acc);

  const int tid = threadIdx.x;
  const int lane = tid & 63;
  const int wave = tid >> 6;
  const int wm = wave & 1, wn = wave >> 1;
  const int l15 = lane & 15, quad = lane >> 4;
#pragma unroll
  for (int j = 0; j < 4; ++j) {
    const int gcol = colBase + wn * 64 + j * 16 + l15;
    const float bval = bo[gcol];
#pragma unroll
    for (int i = 0; i < 8; ++i) {
#pragma unroll
      for (int r = 0; r < 4; ++r) {
        int grow = rowBase + wm * 128 + i * 16 + quad * 4 + r;
        out[(size_t)grow * 1024 + gcol] = acc[i][j][r] + bval;
      }
    }
  }
}

extern "C" void kernel_launch(void* const* d_in, const int* in_sizes, int n_in,
                              void* d_out, int out_size, void* d_ws, size_t ws_size,
                              hipStream_t stream) {
  const float* x  = (const float*)d_in[0];
  const float* Wq = (const float*)d_in[1];
  const float* bq = (const float*)d_in[2];
  const float* Wk = (const float*)d_in[3];
  const float* bk = (const float*)d_in[4];
  const float* Wv = (const float*)d_in[5];
  const float* bv = (const float*)d_in[6];
  const float* Wo = (const float*)d_in[7];
  const float* bo = (const float*)d_in[8];
  float* out = (float*)d_out;

  char* ws = (char*)d_ws;
  short* h    = (short*)(ws);                 // 67,108,864 B (reused as att later)
  short* Wcat = (short*)(ws + 67108864);      //  8,388,608 B ([Wq;Wk;Wv;Wo] bf16)
  short* pq   = (short*)(ws + 75497472);      // 67,108,864 B
  short* pkT  = (short*)(ws + 142606336);     // 67,108,864 B
  short* vT   = (short*)(ws + 209715200);     // 67,108,864 B
  short* kvT  = (short*)(ws + 276824064);     //  4,194,304 B
  float* z    = (float*)(ws + 281018368);     //     65,536 B

  prep_h<<<16384, 256, 0, stream>>>(x, h);
  pack_w<<<4096, 256, 0, stream>>>(Wq, Wk, Wv, Wo, Wcat);
  gemm_qkv<<<dim3(12, 128), 512, 0, stream>>>(h, Wcat, bq, bk, bv, pq, pkT, vT);
  kv_kernel<<<128, 256, 0, stream>>>(pkT, vT, kvT, z);
  attn_kernel<<<dim3(16, 128), 256, 0, stream>>>(pq, kvT, z, h /* att reuses h */);
  gemm_out<<<dim3(4, 128), 512, 0, stream>>>(h, Wcat + 3145728, bo, out);
}

// Round 5
// 685.614 us; speedup vs baseline: 1.6897x; 1.4475x over previous
//
#include <hip/hip_runtime.h>
#include <hip/hip_bf16.h>
#include <stdint.h>

// LMHA: linear multi-head attention (elu+1 feature map), S=2048 B=16 D=1024 H=8 dh=128
// Pipeline: prep_h -> pack_w -> gemm_qkv (bias+elu, coalesced s-major outs via LDS
//           transpose epilogue) -> kv_kernel (reg-staged LDS transpose + kv GEMM + z)
//           -> attn_kernel (num, den, divide) -> gemm_out (+bo)
// R1: m97 128x128 core: latency-bound, 14% MfmaUtil.
// R2: FAILED: 1-D XCD chunk thrashed W in L2.
// R3: 256x256 tile + 2-D XCD partition: FETCH 580->232MB, MfmaUtil unchanged.
// R4: depth-3 counted-vmcnt pipeline + T2 swizzle + T5: bank conflicts -> 0, only +10%.
//     Across R0/R1/R3/R4 gemm_qkv invariant ~600us -> inner loop NOT the limiter.
// R5: epilogue-scatter theory: pkT/vT 2B stores hit 64 lines/instr (e-stride 4KB).
//     Fix: all qkv outputs s-major [B,H,S,dh], written via in-LDS transpose epilogue
//     (full-line dwordx4 stores). kv_kernel does the transpose (reg-staged, LDS
//     stride-44, b64 frag reads) and folds z.

typedef __bf16 bf16x8 __attribute__((ext_vector_type(8)));
typedef float f32x4 __attribute__((ext_vector_type(4)));

#define S_LEN 2048
#define B_SZ  16
#define D_MOD 1024
#define N_H   8
#define D_H   128

__device__ __forceinline__ short f2bf(float f) {
  __bf16 b = (__bf16)f;
  return __builtin_bit_cast(short, b);
}
__device__ __forceinline__ float bf2f(short s) {
  return (float)__builtin_bit_cast(__bf16, s);
}

// async global->LDS, 16B per lane. Dest must be wave-uniform base + lane*16 (linear).
__device__ __forceinline__ void gload_lds16(const short* g, short* l) {
  __builtin_amdgcn_global_load_lds(
      (__attribute__((address_space(1))) void*)(g),
      (__attribute__((address_space(3))) void*)(l), 16, 0, 0);
}

// LDS bank swizzle for 64B rows: XOR byte bits 4-5 with bits 7-8 (row bits 1-2).
__device__ __forceinline__ int swz(int o) { return o ^ (((o >> 7) & 3) << 4); }

// read bf16x8 from 8B-aligned LDS (two b64 reads)
__device__ __forceinline__ bf16x8 ld_bf8_8al(const short* p) {
  union { unsigned long long u[2]; bf16x8 v; } x;
  x.u[0] = *(const unsigned long long*)p;
  x.u[1] = *(const unsigned long long*)(p + 4);
  return x.v;
}

// ---------------- prep: h = bf16(x + pos_encoding) ----------------
__global__ void prep_h(const float* __restrict__ x, short* __restrict__ h) {
  size_t idx8 = (size_t)blockIdx.x * blockDim.x + threadIdx.x; // 8 elems / thread
  size_t base = idx8 * 8;
  int d = (int)(base & 1023);
  int r = (int)(base >> 10);
  int s = r >> 4;
  float4 v0 = *(const float4*)(x + base);
  float4 v1 = *(const float4*)(x + base + 4);
  float vs[8] = {v0.x, v0.y, v0.z, v0.w, v1.x, v1.y, v1.z, v1.w};
  const float kdiv = -9.210340371976184f / 1024.0f;
  bf16x8 ov;
#pragma unroll
  for (int t = 0; t < 8; ++t) {
    int dc = d + t;
    float div = __expf((float)(dc & ~1) * kdiv);
    float ang = (float)s * div;
    float pe = (dc & 1) ? __cosf(ang) : __sinf(ang);
    ov[t] = (__bf16)(vs[t] + pe);
  }
  *(bf16x8*)(h + base) = ov;
}

// ---------------- pack weights to bf16: [Wq;Wk;Wv;Wo] = [4096,1024] ----------------
__global__ void pack_w(const float* __restrict__ Wq, const float* __restrict__ Wk,
                       const float* __restrict__ Wv, const float* __restrict__ Wo,
                       short* __restrict__ Wcat) {
  size_t i4 = (size_t)blockIdx.x * blockDim.x + threadIdx.x;
  size_t base = i4 * 4;
  const float* src;
  size_t off;
  if (base < 1048576)      { src = Wq; off = base; }
  else if (base < 2097152) { src = Wk; off = base - 1048576; }
  else if (base < 3145728) { src = Wv; off = base - 2097152; }
  else                     { src = Wo; off = base - 3145728; }
  float4 v = *(const float4*)(src + off);
  alignas(8) short o[4] = {f2bf(v.x), f2bf(v.y), f2bf(v.z), f2bf(v.w)};
  *(uint2*)(Wcat + base) = *(const uint2*)o;
}

// ================= pipelined GEMM core, 256x256 tile, 512 thr, 8 waves (2M x 4N) ====
// Depth-3 counted-vmcnt pipeline, 4 LDS buffers, one s_barrier per K-tile (see R4).
template <int K>
__device__ __forceinline__ void core_256(const short* __restrict__ A,
                                         const short* __restrict__ W,
                                         char* Lb, f32x4 (&acc)[8][4]) {
  constexpr int NT = K / 32;
  static_assert(NT >= 4, "pipeline needs K >= 128");
  const int tid = threadIdx.x;
  const int lane = tid & 63;
  const int wave = tid >> 6;
  const int wm = wave & 1, wn = wave >> 1;
  const int l15 = lane & 15, quad = lane >> 4;

  const int oA0 = tid * 16, oA1 = 8192 + tid * 16;
  const int lA0 = swz(oA0), lA1 = swz(oA1);
  const short* gA0 = A + (size_t)(lA0 >> 6) * K + ((lA0 & 63) >> 1);
  const short* gA1 = A + (size_t)((lA1 - 8192) >> 6) * K + 128 * K + (((lA1 - 8192) & 63) >> 1);
  const short* gW0 = W + (size_t)(lA0 >> 6) * K + ((lA0 & 63) >> 1);
  const short* gW1 = W + (size_t)((lA1 - 8192) >> 6) * K + 128 * K + (((lA1 - 8192) & 63) >> 1);

  int rA[8], rW[4];
#pragma unroll
  for (int i = 0; i < 8; ++i)
    rA[i] = swz((wm * 128 + i * 16 + l15) * 64 + quad * 16);
#pragma unroll
  for (int j = 0; j < 4; ++j)
    rW[j] = 16384 + swz((wn * 64 + j * 16 + l15) * 64 + quad * 16);

  auto stage = [&](int t) {
    char* sb = Lb + (t & 3) * 32768;
    const int k0 = t * 32;
    gload_lds16(gA0 + k0, (short*)(sb + oA0));
    gload_lds16(gA1 + k0, (short*)(sb + oA1));
    gload_lds16(gW0 + k0, (short*)(sb + 16384 + oA0));
    gload_lds16(gW1 + k0, (short*)(sb + 16384 + oA1));
  };
  auto step = [&](int t, bool do_stage) {
    char* cb = Lb + (t & 3) * 32768;
    bf16x8 af[8], wf[4];
#pragma unroll
    for (int i = 0; i < 8; ++i) af[i] = *(const bf16x8*)(cb + rA[i]);
#pragma unroll
    for (int j = 0; j < 4; ++j) wf[j] = *(const bf16x8*)(cb + rW[j]);
    if (do_stage) stage(t + 3);
    __builtin_amdgcn_s_setprio(1);
#pragma unroll
    for (int i = 0; i < 8; ++i)
#pragma unroll
      for (int j = 0; j < 4; ++j)
        acc[i][j] = __builtin_amdgcn_mfma_f32_16x16x32_bf16(af[i], wf[j], acc[i][j], 0, 0, 0);
    __builtin_amdgcn_s_setprio(0);
    asm volatile("s_waitcnt lgkmcnt(0)" ::: "memory");
    __builtin_amdgcn_sched_barrier(0);
  };

  stage(0); stage(1); stage(2);

  for (int t = 0; t <= NT - 4; ++t) {
    asm volatile("s_waitcnt vmcnt(8)" ::: "memory");
    __builtin_amdgcn_s_barrier();
    step(t, true);
  }
  asm volatile("s_waitcnt vmcnt(8)" ::: "memory");
  __builtin_amdgcn_s_barrier();
  step(NT - 3, false);
  asm volatile("s_waitcnt vmcnt(4)" ::: "memory");
  __builtin_amdgcn_s_barrier();
  step(NT - 2, false);
  asm volatile("s_waitcnt vmcnt(0)" ::: "memory");
  __builtin_amdgcn_s_barrier();
  step(NT - 1, false);
}

// ================= pipelined GEMM core, 128x128 tile, 256 thr, 4 waves (2x2) ========
template <int K>
__device__ __forceinline__ void core_128(const short* __restrict__ A,
                                         const short* __restrict__ W,
                                         char* Lb, f32x4 (&acc)[4][4]) {
  constexpr int NT = K / 32;
  static_assert(NT >= 4, "pipeline needs K >= 128");
  const int tid = threadIdx.x;
  const int lane = tid & 63;
  const int wm = (tid >> 6) & 1, wn = tid >> 7;
  const int l15 = lane & 15, quad = lane >> 4;

  const int oA0 = tid * 16, oA1 = 4096 + tid * 16;
  const int lA0 = swz(oA0), lA1 = swz(oA1);
  const short* gA0 = A + (size_t)(lA0 >> 6) * K + ((lA0 & 63) >> 1);
  const short* gA1 = A + (size_t)((lA1 - 4096) >> 6) * K + 64 * K + (((lA1 - 4096) & 63) >> 1);
  const short* gW0 = W + (size_t)(lA0 >> 6) * K + ((lA0 & 63) >> 1);
  const short* gW1 = W + (size_t)((lA1 - 4096) >> 6) * K + 64 * K + (((lA1 - 4096) & 63) >> 1);

  int rA[4], rW[4];
#pragma unroll
  for (int i = 0; i < 4; ++i)
    rA[i] = swz((wm * 64 + i * 16 + l15) * 64 + quad * 16);
#pragma unroll
  for (int j = 0; j < 4; ++j)
    rW[j] = 8192 + swz((wn * 64 + j * 16 + l15) * 64 + quad * 16);

  auto stage = [&](int t) {
    char* sb = Lb + (t & 3) * 16384;
    const int k0 = t * 32;
    gload_lds16(gA0 + k0, (short*)(sb + oA0));
    gload_lds16(gA1 + k0, (short*)(sb + oA1));
    gload_lds16(gW0 + k0, (short*)(sb + 8192 + oA0));
    gload_lds16(gW1 + k0, (short*)(sb + 8192 + oA1));
  };
  auto step = [&](int t, bool do_stage) {
    char* cb = Lb + (t & 3) * 16384;
    bf16x8 af[4], wf[4];
#pragma unroll
    for (int i = 0; i < 4; ++i) af[i] = *(const bf16x8*)(cb + rA[i]);
#pragma unroll
    for (int j = 0; j < 4; ++j) wf[j] = *(const bf16x8*)(cb + rW[j]);
    if (do_stage) stage(t + 3);
    __builtin_amdgcn_s_setprio(1);
#pragma unroll
    for (int i = 0; i < 4; ++i)
#pragma unroll
      for (int j = 0; j < 4; ++j)
        acc[i][j] = __builtin_amdgcn_mfma_f32_16x16x32_bf16(af[i], wf[j], acc[i][j], 0, 0, 0);
    __builtin_amdgcn_s_setprio(0);
    asm volatile("s_waitcnt lgkmcnt(0)" ::: "memory");
    __builtin_amdgcn_sched_barrier(0);
  };

  stage(0); stage(1); stage(2);

  for (int t = 0; t <= NT - 4; ++t) {
    asm volatile("s_waitcnt vmcnt(8)" ::: "memory");
    __builtin_amdgcn_s_barrier();
    step(t, true);
  }
  asm volatile("s_waitcnt vmcnt(8)" ::: "memory");
  __builtin_amdgcn_s_barrier();
  step(NT - 3, false);
  asm volatile("s_waitcnt vmcnt(4)" ::: "memory");
  __builtin_amdgcn_s_barrier();
  step(NT - 2, false);
  asm volatile("s_waitcnt vmcnt(0)" ::: "memory");
  __builtin_amdgcn_s_barrier();
  step(NT - 1, false);
}

// ---------------- GEMM1: qkv = h @ Wqkv^T, fused bias + elu+1 ----------------
// Outputs ALL s-major [B,H,S,dh]: pq, pk (elu+1), pv (plain).
// Epilogue: acc -> LDS [256 rows][256 cols] bf16 (XOR c bits 3-5 with row bits 0-2),
// then 16-lane groups store full 256B-contiguous e-runs (full-line dwordx4).
__launch_bounds__(512, 2)
__global__ void gemm_qkv(const short* __restrict__ h, const short* __restrict__ Wqkv,
                         const float* __restrict__ bq, const float* __restrict__ bk,
                         const float* __restrict__ bv,
                         short* __restrict__ pq, short* __restrict__ pk,
                         short* __restrict__ pv) {
  __shared__ alignas(16) char Lb[131072];
  const int lin = blockIdx.y * 12 + blockIdx.x; // 0..1535
  const int x = lin & 7, q = lin >> 3;          // q 0..191
  const int xm = x >> 1, xn = x & 1;
  const int bm = xm * 32 + q / 6;               // 0..127
  const int bn = xn * 6 + q % 6;                // 0..11
  const int rowBase = bm * 256, colBase = bn * 256;

  f32x4 acc[8][4] = {};
  core_256<1024>(h + (size_t)rowBase * 1024, Wqkv + (size_t)colBase * 1024, Lb, acc);

  const int tid = threadIdx.x;
  const int lane = tid & 63;
  const int wave = tid >> 6;
  const int wm = wave & 1, wn = wave >> 1;
  const int l15 = lane & 15, quad = lane >> 4;

  const int p = bn >> 2; // 0:q 1:k 2:v
  const float* bias = (p == 0) ? bq : (p == 1) ? bk : bv;
  short* Pout = (p == 0) ? pq : (p == 1) ? pk : pv;

  __syncthreads(); // core fully drained on ALL waves before Lb reuse
  short* Lt = (short*)Lb; // [256][256] bf16 = 128KB
#pragma unroll
  for (int j = 0; j < 4; ++j) {
    const int c = wn * 64 + j * 16 + l15; // 0..255
    const float bval = bias[(bn & 3) * 256 + c];
#pragma unroll
    for (int i = 0; i < 8; ++i) {
#pragma unroll
      for (int r = 0; r < 4; ++r) {
        const int mloc = wm * 128 + i * 16 + quad * 4 + r;
        float v = acc[i][j][r] + bval;
        if (p < 2) v = v > 0.f ? v + 1.f : __expf(v); // elu+1 for q,k
        Lt[mloc * 256 + (c ^ ((mloc & 7) << 3))] = f2bf(v);
      }
    }
  }
  __syncthreads();
  // read-back: 512 chunks of 256B (one per (row, head-half)); 16 lanes cooperate
  // per chunk -> full 64B lines.
  const int g16 = tid >> 4, L = tid & 15;
#pragma unroll
  for (int it = 0; it < 16; ++it) {
    const int chunk = it * 32 + g16;       // 0..511
    const int row = chunk >> 1, hhl = chunk & 1;
    const int grow = rowBase + row;
    const int s = grow >> 4, b = grow & 15;
    const int hh = (bn & 3) * 2 + hhl;
    const short* src = Lt + row * 256 + ((hhl * 128 + L * 8) ^ ((row & 7) << 3));
    short* dst = Pout + (((size_t)b * N_H + hh) * S_LEN + s) * D_H + L * 8;
    *(uint4*)dst = *(const uint4*)src;
  }
}

// ---------------- kv state: kvT[bh][e][d] = sum_s pv[s][e]*pk[s][d]; z[bh][d] -------
// Consumes s-major pk/pv. Per 32-s tile: reg-staged coalesced loads -> transposed
// LDS tiles Vt/Pt [128][44] (stride 44 shorts: 8B-aligned b64 frag reads, spread
// banks) -> 16 MFMA per wave. Loads for tile t+1 issued before MFMA phase (T14).
__launch_bounds__(256, 2)
__global__ void kv_kernel(const short* __restrict__ pk, const short* __restrict__ pv,
                          short* __restrict__ kvT, float* __restrict__ z) {
  __shared__ alignas(16) short Vt[128 * 44];
  __shared__ alignas(16) short Pt[128 * 44];
  __shared__ float zl[16 * 128];
  const int bh = blockIdx.x; // 0..127
  const short* Vg = pv + (size_t)bh * S_LEN * D_H;
  const short* Pg = pk + (size_t)bh * S_LEN * D_H;

  const int tid = threadIdx.x;
  const int lane = tid & 63;
  const int wm = (tid >> 6) & 1, wn = tid >> 7;
  const int l15 = lane & 15, quad = lane >> 4;
  const int s_loc = tid >> 3, e8 = tid & 7; // stage: s row 0..31, e-octet 0..7

  const short* vsrc = Vg + s_loc * 128 + e8 * 8;
  const short* psrc = Pg + s_loc * 128 + e8 * 8;

  f32x4 acc[4][4] = {};
  uint4 cv0, cv1, cp0, cp1;
  cv0 = *(const uint4*)(vsrc);
  cv1 = *(const uint4*)(vsrc + 64);
  cp0 = *(const uint4*)(psrc);
  cp1 = *(const uint4*)(psrc + 64);

  for (int t = 0; t < 64; ++t) {
    __builtin_amdgcn_s_barrier(); // all waves done reading LDS tile t-1
    // transposed LDS writes of tile t (compiler inserts vmcnt waits for regs)
    const short* sv0 = (const short*)&cv0;
    const short* sv1 = (const short*)&cv1;
    const short* sp0 = (const short*)&cp0;
    const short* sp1 = (const short*)&cp1;
#pragma unroll
    for (int u = 0; u < 8; ++u) {
      Vt[(e8 * 8 + u) * 44 + s_loc] = sv0[u];
      Vt[(64 + e8 * 8 + u) * 44 + s_loc] = sv1[u];
      Pt[(e8 * 8 + u) * 44 + s_loc] = sp0[u];
      Pt[(64 + e8 * 8 + u) * 44 + s_loc] = sp1[u];
    }
    if (t < 63) { // issue tile t+1 loads; they fly under the MFMA phase
      const int o = (t + 1) * 32 * 128;
      cv0 = *(const uint4*)(vsrc + o);
      cv1 = *(const uint4*)(vsrc + o + 64);
      cp0 = *(const uint4*)(psrc + o);
      cp1 = *(const uint4*)(psrc + o + 64);
    }
    asm volatile("s_waitcnt lgkmcnt(0)" ::: "memory"); // my ds_writes done
    __builtin_amdgcn_sched_barrier(0);
    __builtin_amdgcn_s_barrier(); // everyone's writes visible
    bf16x8 af[4], wf[4];
#pragma unroll
    for (int i = 0; i < 4; ++i)
      af[i] = ld_bf8_8al(&Vt[(wm * 64 + i * 16 + l15) * 44 + quad * 8]);
#pragma unroll
    for (int j = 0; j < 4; ++j)
      wf[j] = ld_bf8_8al(&Pt[(wn * 64 + j * 16 + l15) * 44 + quad * 8]);
#pragma unroll
    for (int i = 0; i < 4; ++i)
#pragma unroll
      for (int j = 0; j < 4; ++j)
        acc[i][j] = __builtin_amdgcn_mfma_f32_16x16x32_bf16(af[i], wf[j], acc[i][j], 0, 0, 0);
    asm volatile("s_waitcnt lgkmcnt(0)" ::: "memory"); // frag reads done
    __builtin_amdgcn_sched_barrier(0);
  }

  // write kvT[bh][e][d] bf16
#pragma unroll
  for (int j = 0; j < 4; ++j) {
    const int d = wn * 64 + j * 16 + l15;
#pragma unroll
    for (int i = 0; i < 4; ++i) {
#pragma unroll
      for (int r = 0; r < 4; ++r) {
        const int e = wm * 64 + i * 16 + quad * 4 + r;
        kvT[(size_t)bh * (D_H * D_H) + (size_t)e * D_H + d] = f2bf(acc[i][j][r]);
      }
    }
  }
  // z[d] = sum_s pk[s][d]  (coalesced s-major reads, L2-hot)
  __syncthreads();
  {
    const int d8 = tid & 15, so = tid >> 4; // 16 d-octets x 16 s-phases
    float za[8] = {};
    for (int s = so; s < S_LEN; s += 16) {
      uint4 u = *(const uint4*)(Pg + (size_t)s * 128 + d8 * 8);
      const short* sp = (const short*)&u;
#pragma unroll
      for (int u2 = 0; u2 < 8; ++u2) za[u2] += bf2f(sp[u2]);
    }
#pragma unroll
    for (int u2 = 0; u2 < 8; ++u2) zl[so * 128 + d8 * 8 + u2] = za[u2];
  }
  __syncthreads();
  if (tid < 128) {
    float sum = 0.f;
#pragma unroll
    for (int k = 0; k < 16; ++k) sum += zl[k * 128 + tid];
    z[bh * D_H + tid] = sum;
  }
}

// ---------------- num/den/divide: att = (pq @ kv) / (pq . z + eps) ----------------
__launch_bounds__(256, 2)
__global__ void attn_kernel(const short* __restrict__ pq, const short* __restrict__ kvT,
                            const float* __restrict__ z, short* __restrict__ att) {
  __shared__ alignas(16) char Lb[65536];
  __shared__ float den_lds[128];
  __shared__ float z_lds[128];
  const int s0 = blockIdx.x * 128; // 16 tiles over S
  const int bh = blockIdx.y;       // 0..127
  const int tid = threadIdx.x;

  const short* Abase = pq + ((size_t)bh * S_LEN + s0) * D_H; // rows = s
  const short* Wbase = kvT + (size_t)bh * (D_H * D_H);       // rows = e, cols = d

  f32x4 acc[4][4] = {};
  core_128<128>(Abase, Wbase, Lb, acc);

  if (tid < 128) z_lds[tid] = z[bh * D_H + tid];
  __syncthreads();
  if (tid < 128) {
    const short* prow = Abase + (size_t)tid * D_H;
    float sum = 0.f;
#pragma unroll
    for (int d = 0; d < D_H; d += 8) {
      bf16x8 vv = *(const bf16x8*)(prow + d);
#pragma unroll
      for (int t = 0; t < 8; ++t) sum += (float)vv[t] * z_lds[d + t];
    }
    den_lds[tid] = sum + 1e-6f;
  }
  __syncthreads();

  const int lane = tid & 63;
  const int wm = (tid >> 6) & 1, wn = tid >> 7;
  const int l15 = lane & 15, quad = lane >> 4;
  const int b = bh >> 3, hd = bh & 7;
#pragma unroll
  for (int j = 0; j < 4; ++j) {
    const int e = wn * 64 + j * 16 + l15;
#pragma unroll
    for (int i = 0; i < 4; ++i) {
#pragma unroll
      for (int r = 0; r < 4; ++r) {
        int mloc = wm * 64 + i * 16 + quad * 4 + r; // s_local
        float a = acc[i][j][r] / den_lds[mloc];
        att[((size_t)(s0 + mloc) * B_SZ + b) * D_MOD + hd * D_H + e] = f2bf(a);
      }
    }
  }
}

// ---------------- out = att @ Wo^T + bo (fp32 out), 256x256 tiles ----------------
__launch_bounds__(512, 2)
__global__ void gemm_out(const short* __restrict__ att, const short* __restrict__ WoB,
                         const float* __restrict__ bo, float* __restrict__ out) {
  __shared__ alignas(16) char Lb[131072];
  const int lin = blockIdx.y * 4 + blockIdx.x; // 0..511
  const int x = lin & 7, q = lin >> 3;         // q 0..63
  const int bn = q & 3;                        // 0..3
  const int bm = x * 16 + (q >> 2);            // 0..127
  const int rowBase = bm * 256, colBase = bn * 256;

  f32x4 acc[8][4] = {};
  core_256<1024>(att + (size_t)rowBase * 1024, WoB + (size_t)colBase * 1024, Lb, acc);

  const int tid = threadIdx.x;
  const int lane = tid & 63;
  const int wave = tid >> 6;
  const int wm = wave & 1, wn = wave >> 1;
  const int l15 = lane & 15, quad = lane >> 4;
#pragma unroll
  for (int j = 0; j < 4; ++j) {
    const int gcol = colBase + wn * 64 + j * 16 + l15;
    const float bval = bo[gcol];
#pragma unroll
    for (int i = 0; i < 8; ++i) {
#pragma unroll
      for (int r = 0; r < 4; ++r) {
        int grow = rowBase + wm * 128 + i * 16 + quad * 4 + r;
        out[(size_t)grow * 1024 + gcol] = acc[i][j][r] + bval;
      }
    }
  }
}

extern "C" void kernel_launch(void* const* d_in, const int* in_sizes, int n_in,
                              void* d_out, int out_size, void* d_ws, size_t ws_size,
                              hipStream_t stream) {
  const float* x  = (const float*)d_in[0];
  const float* Wq = (const float*)d_in[1];
  const float* bq = (const float*)d_in[2];
  const float* Wk = (const float*)d_in[3];
  const float* bk = (const float*)d_in[4];
  const float* Wv = (const float*)d_in[5];
  const float* bv = (const float*)d_in[6];
  const float* Wo = (const float*)d_in[7];
  const float* bo = (const float*)d_in[8];
  float* out = (float*)d_out;

  char* ws = (char*)d_ws;
  short* h    = (short*)(ws);                 // 67,108,864 B (reused as att later)
  short* Wcat = (short*)(ws + 67108864);      //  8,388,608 B ([Wq;Wk;Wv;Wo] bf16)
  short* pq   = (short*)(ws + 75497472);      // 67,108,864 B  [B,H,S,dh]
  short* pk   = (short*)(ws + 142606336);     // 67,108,864 B  [B,H,S,dh]
  short* pv   = (short*)(ws + 209715200);     // 67,108,864 B  [B,H,S,dh]
  short* kvT  = (short*)(ws + 276824064);     //  4,194,304 B
  float* z    = (float*)(ws + 281018368);     //     65,536 B

  prep_h<<<16384, 256, 0, stream>>>(x, h);
  pack_w<<<4096, 256, 0, stream>>>(Wq, Wk, Wv, Wo, Wcat);
  gemm_qkv<<<dim3(12, 128), 512, 0, stream>>>(h, Wcat, bq, bk, bv, pq, pk, pv);
  kv_kernel<<<128, 256, 0, stream>>>(pk, pv, kvT, z);
  attn_kernel<<<dim3(16, 128), 256, 0, stream>>>(pq, kvT, z, h /* att reuses h */);
  gemm_out<<<dim3(4, 128), 512, 0, stream>>>(h, Wcat + 3145728, bo, out);
}

// Round 6
// 637.341 us; speedup vs baseline: 1.8177x; 1.0757x over previous
//
#include <hip/hip_runtime.h>
#include <hip/hip_bf16.h>
#include <stdint.h>

// LMHA: linear multi-head attention (elu+1 feature map), S=2048 B=16 D=1024 H=8 dh=128
// Pipeline: prep_h -> pack_w -> gemm_qkv (bias+elu, s-major outs via LDS transpose
//           epilogue) -> kv_part (x4 S-split partials) -> kv_reduce -> attn_kernel
//           -> gemm_out (+bo)
// R1-R4: see git log. R5: scatter-free epilogues: qkv 598->240us (MfmaUtil 38%).
// R6: (a) 8-phase fine-interleave core (T3+T4, m201 template) for gemm_qkv/gemm_out:
//     BK=64, K-half staging units, 2 buffers (128KB), phase = {ds_read 4-8, stage 1
//     half-tile (2 gloads), barrier, lgkm0, 16 MFMA, barrier}; vmcnt(6) at phases
//     4/8 only (2 loads x 3 half-tiles in flight). Each stage targets the region
//     freed one phase earlier -> race-free. (b) kv S-split x4: 512 blocks (was 128,
//     half-GPU idle), fp32 partials in dead h-region + kv_reduce.

typedef __bf16 bf16x8 __attribute__((ext_vector_type(8)));
typedef float f32x4 __attribute__((ext_vector_type(4)));

#define S_LEN 2048
#define B_SZ  16
#define D_MOD 1024
#define N_H   8
#define D_H   128

__device__ __forceinline__ short f2bf(float f) {
  __bf16 b = (__bf16)f;
  return __builtin_bit_cast(short, b);
}
__device__ __forceinline__ float bf2f(short s) {
  return (float)__builtin_bit_cast(__bf16, s);
}

// async global->LDS, 16B per lane. Dest must be wave-uniform base + lane*16 (linear).
__device__ __forceinline__ void gload_lds16(const short* g, short* l) {
  __builtin_amdgcn_global_load_lds(
      (__attribute__((address_space(1))) void*)(g),
      (__attribute__((address_space(3))) void*)(l), 16, 0, 0);
}

// LDS bank swizzle for 64B rows within a [rows][64B] block: XOR byte bits 4-5 with
// row bits 1-2 (offset bits 7-8). Involution; 16-row frag reads -> 2 lanes/bank (free).
__device__ __forceinline__ int swz(int o) { return o ^ (((o >> 7) & 3) << 4); }

// read bf16x8 from 8B-aligned LDS (two b64 reads)
__device__ __forceinline__ bf16x8 ld_bf8_8al(const short* p) {
  union { unsigned long long u[2]; bf16x8 v; } x;
  x.u[0] = *(const unsigned long long*)p;
  x.u[1] = *(const unsigned long long*)(p + 4);
  return x.v;
}

// ---------------- prep: h = bf16(x + pos_encoding) ----------------
__global__ void prep_h(const float* __restrict__ x, short* __restrict__ h) {
  size_t idx8 = (size_t)blockIdx.x * blockDim.x + threadIdx.x; // 8 elems / thread
  size_t base = idx8 * 8;
  int d = (int)(base & 1023);
  int r = (int)(base >> 10);
  int s = r >> 4;
  float4 v0 = *(const float4*)(x + base);
  float4 v1 = *(const float4*)(x + base + 4);
  float vs[8] = {v0.x, v0.y, v0.z, v0.w, v1.x, v1.y, v1.z, v1.w};
  const float kdiv = -9.210340371976184f / 1024.0f;
  bf16x8 ov;
#pragma unroll
  for (int t = 0; t < 8; ++t) {
    int dc = d + t;
    float div = __expf((float)(dc & ~1) * kdiv);
    float ang = (float)s * div;
    float pe = (dc & 1) ? __cosf(ang) : __sinf(ang);
    ov[t] = (__bf16)(vs[t] + pe);
  }
  *(bf16x8*)(h + base) = ov;
}

// ---------------- pack weights to bf16: [Wq;Wk;Wv;Wo] = [4096,1024] ----------------
__global__ void pack_w(const float* __restrict__ Wq, const float* __restrict__ Wk,
                       const float* __restrict__ Wv, const float* __restrict__ Wo,
                       short* __restrict__ Wcat) {
  size_t i4 = (size_t)blockIdx.x * blockDim.x + threadIdx.x;
  size_t base = i4 * 4;
  const float* src;
  size_t off;
  if (base < 1048576)      { src = Wq; off = base; }
  else if (base < 2097152) { src = Wk; off = base - 1048576; }
  else if (base < 3145728) { src = Wv; off = base - 2097152; }
  else                     { src = Wo; off = base - 3145728; }
  float4 v = *(const float4*)(src + off);
  alignas(8) short o[4] = {f2bf(v.x), f2bf(v.y), f2bf(v.z), f2bf(v.w)};
  *(uint2*)(Wcat + base) = *(const uint2*)o;
}

// ================= 8-phase GEMM core, 256x256 tile, BK=64, 512 thr, 8 waves ========
// LDS: 2 buffers x [A kh0 16K | A kh1 16K | B kh0 16K | B kh1 16K] = 128 KB.
// Each kh block = [256 rows][32 k shorts] (64B rows, swz'd).
// Phase p in 0..7: tile tau = t+(p>>2), kh = (p>>1)&1, ih = p&1.
//   reads: ih==0 -> wf[0..3](kh) + af[0..3]; ih==1 -> af[4..7] (wf reused)
//   stage: 1 half-tile (2 gloads) into the region freed last phase.
//   barrier; lgkm0; 16 MFMA (acc[ih*4+i][j]); barrier.
// vmcnt(6) at p3/p7 (= 2 loads x 3 half-tiles in flight). All half-tiles have
// 6-7 phases of flight before first read.
template <int K>
__device__ __forceinline__ void core_256(const short* __restrict__ A,
                                         const short* __restrict__ W,
                                         char* Lb, f32x4 (&acc)[8][4]) {
  constexpr int NT = K / 64;
  static_assert(NT >= 4 && (NT & 1) == 0, "K must be multiple of 128, >= 256");
  const int tid = threadIdx.x;
  const int lane = tid & 63;
  const int wave = tid >> 6;
  const int wm = wave & 1, wn = wave >> 1;
  const int l15 = lane & 15, quad = lane >> 4;

  // staging: linear LDS dest o in [0,16384) per kh-block; source col pre-swizzled
  const int o0 = tid * 16, o1 = 8192 + tid * 16;
  const int r0s = o0 >> 6, r1s = o1 >> 6;
  const int c0 = ((o0 & 63) ^ (((o0 >> 7) & 3) << 4)) >> 1;
  const int c1 = ((o1 & 63) ^ (((o1 >> 7) & 3) << 4)) >> 1;
  const short* gA0 = A + (size_t)r0s * K + c0;
  const short* gA1 = A + (size_t)r1s * K + c1;
  const short* gW0 = W + (size_t)r0s * K + c0;
  const short* gW1 = W + (size_t)r1s * K + c1;

  int rAo[8], rWo[4];
#pragma unroll
  for (int i = 0; i < 8; ++i)
    rAo[i] = swz((wm * 128 + i * 16 + l15) * 64 + quad * 16);
#pragma unroll
  for (int j = 0; j < 4; ++j)
    rWo[j] = swz((wn * 64 + j * 16 + l15) * 64 + quad * 16);

  bf16x8 af[4], wf[4];

  auto stg = [&](int tau, int op, int kh) { // op: 0=A 1=B
    char* d = Lb + (tau & 1) * 65536 + op * 32768 + kh * 16384;
    const int ko = tau * 64 + kh * 32;
    const short* s0 = (op ? gW0 : gA0) + ko;
    const short* s1 = (op ? gW1 : gA1) + ko;
    gload_lds16(s0, (short*)(d + o0));
    gload_lds16(s1, (short*)(d + o1));
  };
  auto rd0 = [&](int tau, int kh) { // ih==0: wf + af[0..3]
    char* base = Lb + (tau & 1) * 65536 + kh * 16384;
#pragma unroll
    for (int j = 0; j < 4; ++j) wf[j] = *(const bf16x8*)(base + 32768 + rWo[j]);
#pragma unroll
    for (int i = 0; i < 4; ++i) af[i] = *(const bf16x8*)(base + rAo[i]);
  };
  auto rd1 = [&](int tau, int kh) { // ih==1: af[4..7]
    char* base = Lb + (tau & 1) * 65536 + kh * 16384;
#pragma unroll
    for (int i = 0; i < 4; ++i) af[i] = *(const bf16x8*)(base + rAo[4 + i]);
  };
  auto mm = [&](int ih) {
    __builtin_amdgcn_s_barrier();
    asm volatile("s_waitcnt lgkmcnt(0)" ::: "memory");
    __builtin_amdgcn_sched_barrier(0);
    __builtin_amdgcn_s_setprio(1);
#pragma unroll
    for (int i = 0; i < 4; ++i)
#pragma unroll
      for (int j = 0; j < 4; ++j)
        acc[ih * 4 + i][j] =
            __builtin_amdgcn_mfma_f32_16x16x32_bf16(af[i], wf[j], acc[ih * 4 + i][j], 0, 0, 0);
    __builtin_amdgcn_s_setprio(0);
    __builtin_amdgcn_s_barrier();
  };

  // prologue: tile0 all 4 halves + tile1 {Bkh0, Akh0, Bkh1}; Akh1(1) staged at p0.
  stg(0, 1, 0); stg(0, 0, 0); stg(0, 1, 1); stg(0, 0, 1);
  stg(1, 1, 0); stg(1, 0, 0); stg(1, 1, 1);
  asm volatile("s_waitcnt vmcnt(6)" ::: "memory"); // tile0 landed
  __builtin_amdgcn_s_barrier();

  for (int t = 0; t + 3 < NT; t += 2) {
    rd0(t, 0);     stg(t + 1, 0, 1);                                          mm(0); // p0
    rd1(t, 0);     stg(t + 2, 1, 0);                                          mm(1); // p1
    rd0(t, 1);     stg(t + 2, 0, 0);                                          mm(0); // p2
    rd1(t, 1);     stg(t + 2, 1, 1);
    asm volatile("s_waitcnt vmcnt(6)" ::: "memory");                          mm(1); // p3
    rd0(t + 1, 0); stg(t + 2, 0, 1);                                          mm(0); // p4
    rd1(t + 1, 0); stg(t + 3, 1, 0);                                          mm(1); // p5
    rd0(t + 1, 1); stg(t + 3, 0, 0);                                          mm(0); // p6
    rd1(t + 1, 1); stg(t + 3, 1, 1);
    asm volatile("s_waitcnt vmcnt(6)" ::: "memory");                          mm(1); // p7
  }
  { // final iter: t = NT-2; only p0's Akh1(t+1) stage; vmcnt(0) at p3.
    const int t = NT - 2;
    rd0(t, 0);     stg(t + 1, 0, 1);                                          mm(0);
    rd1(t, 0);                                                                mm(1);
    rd0(t, 1);                                                                mm(0);
    rd1(t, 1);
    asm volatile("s_waitcnt vmcnt(0)" ::: "memory");                          mm(1);
    rd0(t + 1, 0);                                                            mm(0);
    rd1(t + 1, 0);                                                            mm(1);
    rd0(t + 1, 1);                                                            mm(0);
    rd1(t + 1, 1);                                                            mm(1);
  }
}

// ================= pipelined GEMM core, 128x128 tile, 256 thr (attn only) ==========
template <int K>
__device__ __forceinline__ void core_128(const short* __restrict__ A,
                                         const short* __restrict__ W,
                                         char* Lb, f32x4 (&acc)[4][4]) {
  constexpr int NT = K / 32;
  static_assert(NT >= 4, "pipeline needs K >= 128");
  const int tid = threadIdx.x;
  const int lane = tid & 63;
  const int wm = (tid >> 6) & 1, wn = tid >> 7;
  const int l15 = lane & 15, quad = lane >> 4;

  const int oA0 = tid * 16, oA1 = 4096 + tid * 16;
  const int lA0 = swz(oA0), lA1 = swz(oA1);
  const short* gA0 = A + (size_t)(lA0 >> 6) * K + ((lA0 & 63) >> 1);
  const short* gA1 = A + (size_t)((lA1 - 4096) >> 6) * K + 64 * K + (((lA1 - 4096) & 63) >> 1);
  const short* gW0 = W + (size_t)(lA0 >> 6) * K + ((lA0 & 63) >> 1);
  const short* gW1 = W + (size_t)((lA1 - 4096) >> 6) * K + 64 * K + (((lA1 - 4096) & 63) >> 1);

  int rA[4], rW[4];
#pragma unroll
  for (int i = 0; i < 4; ++i)
    rA[i] = swz((wm * 64 + i * 16 + l15) * 64 + quad * 16);
#pragma unroll
  for (int j = 0; j < 4; ++j)
    rW[j] = 8192 + swz((wn * 64 + j * 16 + l15) * 64 + quad * 16);

  auto stage = [&](int t) {
    char* sb = Lb + (t & 3) * 16384;
    const int k0 = t * 32;
    gload_lds16(gA0 + k0, (short*)(sb + oA0));
    gload_lds16(gA1 + k0, (short*)(sb + oA1));
    gload_lds16(gW0 + k0, (short*)(sb + 8192 + oA0));
    gload_lds16(gW1 + k0, (short*)(sb + 8192 + oA1));
  };
  auto step = [&](int t, bool do_stage) {
    char* cb = Lb + (t & 3) * 16384;
    bf16x8 af[4], wf[4];
#pragma unroll
    for (int i = 0; i < 4; ++i) af[i] = *(const bf16x8*)(cb + rA[i]);
#pragma unroll
    for (int j = 0; j < 4; ++j) wf[j] = *(const bf16x8*)(cb + rW[j]);
    if (do_stage) stage(t + 3);
    __builtin_amdgcn_s_setprio(1);
#pragma unroll
    for (int i = 0; i < 4; ++i)
#pragma unroll
      for (int j = 0; j < 4; ++j)
        acc[i][j] = __builtin_amdgcn_mfma_f32_16x16x32_bf16(af[i], wf[j], acc[i][j], 0, 0, 0);
    __builtin_amdgcn_s_setprio(0);
    asm volatile("s_waitcnt lgkmcnt(0)" ::: "memory");
    __builtin_amdgcn_sched_barrier(0);
  };

  stage(0); stage(1); stage(2);

  for (int t = 0; t <= NT - 4; ++t) {
    asm volatile("s_waitcnt vmcnt(8)" ::: "memory");
    __builtin_amdgcn_s_barrier();
    step(t, true);
  }
  asm volatile("s_waitcnt vmcnt(8)" ::: "memory");
  __builtin_amdgcn_s_barrier();
  step(NT - 3, false);
  asm volatile("s_waitcnt vmcnt(4)" ::: "memory");
  __builtin_amdgcn_s_barrier();
  step(NT - 2, false);
  asm volatile("s_waitcnt vmcnt(0)" ::: "memory");
  __builtin_amdgcn_s_barrier();
  step(NT - 1, false);
}

// ---------------- GEMM1: qkv = h @ Wqkv^T, fused bias + elu+1 ----------------
// Outputs ALL s-major [B,H,S,dh]: pq, pk (elu+1), pv (plain). LDS transpose epilogue.
__launch_bounds__(512, 1)
__global__ void gemm_qkv(const short* __restrict__ h, const short* __restrict__ Wqkv,
                         const float* __restrict__ bq, const float* __restrict__ bk,
                         const float* __restrict__ bv,
                         short* __restrict__ pq, short* __restrict__ pk,
                         short* __restrict__ pv) {
  __shared__ alignas(16) char Lb[131072];
  const int lin = blockIdx.y * 12 + blockIdx.x; // 0..1535
  const int x = lin & 7, q = lin >> 3;          // q 0..191
  const int xm = x >> 1, xn = x & 1;
  const int bm = xm * 32 + q / 6;               // 0..127
  const int bn = xn * 6 + q % 6;                // 0..11
  const int rowBase = bm * 256, colBase = bn * 256;

  f32x4 acc[8][4] = {};
  core_256<1024>(h + (size_t)rowBase * 1024, Wqkv + (size_t)colBase * 1024, Lb, acc);

  const int tid = threadIdx.x;
  const int lane = tid & 63;
  const int wave = tid >> 6;
  const int wm = wave & 1, wn = wave >> 1;
  const int l15 = lane & 15, quad = lane >> 4;

  const int p = bn >> 2; // 0:q 1:k 2:v
  const float* bias = (p == 0) ? bq : (p == 1) ? bk : bv;
  short* Pout = (p == 0) ? pq : (p == 1) ? pk : pv;

  __syncthreads(); // core fully drained on ALL waves before Lb reuse
  short* Lt = (short*)Lb; // [256][256] bf16 = 128KB
#pragma unroll
  for (int j = 0; j < 4; ++j) {
    const int c = wn * 64 + j * 16 + l15; // 0..255
    const float bval = bias[(bn & 3) * 256 + c];
#pragma unroll
    for (int i = 0; i < 8; ++i) {
#pragma unroll
      for (int r = 0; r < 4; ++r) {
        const int mloc = wm * 128 + i * 16 + quad * 4 + r;
        float v = acc[i][j][r] + bval;
        if (p < 2) v = v > 0.f ? v + 1.f : __expf(v); // elu+1 for q,k
        Lt[mloc * 256 + (c ^ ((mloc & 7) << 3))] = f2bf(v);
      }
    }
  }
  __syncthreads();
  // read-back: 512 chunks of 256B; 16 lanes cooperate per chunk -> full 64B lines.
  const int g16 = tid >> 4, L = tid & 15;
#pragma unroll
  for (int it = 0; it < 16; ++it) {
    const int chunk = it * 32 + g16;       // 0..511
    const int row = chunk >> 1, hhl = chunk & 1;
    const int grow = rowBase + row;
    const int s = grow >> 4, b = grow & 15;
    const int hh = (bn & 3) * 2 + hhl;
    const short* src = Lt + row * 256 + ((hhl * 128 + L * 8) ^ ((row & 7) << 3));
    short* dst = Pout + (((size_t)b * N_H + hh) * S_LEN + s) * D_H + L * 8;
    *(uint4*)dst = *(const uint4*)src;
  }
}

// ---------------- kv partial: kvp[bh4s][e][d] = sum_{s in split} pv[s][e]*pk[s][d] --
// S-split x4: 512 blocks (2/CU). Reg-staged transpose into [128][44] LDS, MFMA.
__launch_bounds__(256, 2)
__global__ void kv_part(const short* __restrict__ pk, const short* __restrict__ pv,
                        float* __restrict__ kvp, float* __restrict__ zp) {
  __shared__ alignas(16) short Vt[128 * 44];
  __shared__ alignas(16) short Pt[128 * 44];
  __shared__ float zl[16 * 128];
  const int split = blockIdx.x; // 0..3
  const int bh = blockIdx.y;    // 0..127
  const int sbase = split * 512;
  const short* Vg = pv + ((size_t)bh * S_LEN + sbase) * D_H;
  const short* Pg = pk + ((size_t)bh * S_LEN + sbase) * D_H;

  const int tid = threadIdx.x;
  const int lane = tid & 63;
  const int wm = (tid >> 6) & 1, wn = tid >> 7;
  const int l15 = lane & 15, quad = lane >> 4;
  const int s_loc = tid >> 3, e8 = tid & 7; // stage: s row 0..31, e-octet 0..7

  const short* vsrc = Vg + s_loc * 128 + e8 * 8;
  const short* psrc = Pg + s_loc * 128 + e8 * 8;

  f32x4 acc[4][4] = {};
  uint4 cv0, cv1, cp0, cp1;
  cv0 = *(const uint4*)(vsrc);
  cv1 = *(const uint4*)(vsrc + 64);
  cp0 = *(const uint4*)(psrc);
  cp1 = *(const uint4*)(psrc + 64);

  for (int t = 0; t < 16; ++t) {
    __builtin_amdgcn_s_barrier();
    const short* sv0 = (const short*)&cv0;
    const short* sv1 = (const short*)&cv1;
    const short* sp0 = (const short*)&cp0;
    const short* sp1 = (const short*)&cp1;
#pragma unroll
    for (int u = 0; u < 8; ++u) {
      Vt[(e8 * 8 + u) * 44 + s_loc] = sv0[u];
      Vt[(64 + e8 * 8 + u) * 44 + s_loc] = sv1[u];
      Pt[(e8 * 8 + u) * 44 + s_loc] = sp0[u];
      Pt[(64 + e8 * 8 + u) * 44 + s_loc] = sp1[u];
    }
    if (t < 15) {
      const int o = (t + 1) * 32 * 128;
      cv0 = *(const uint4*)(vsrc + o);
      cv1 = *(const uint4*)(vsrc + o + 64);
      cp0 = *(const uint4*)(psrc + o);
      cp1 = *(const uint4*)(psrc + o + 64);
    }
    asm volatile("s_waitcnt lgkmcnt(0)" ::: "memory");
    __builtin_amdgcn_sched_barrier(0);
    __builtin_amdgcn_s_barrier();
    bf16x8 af[4], wf[4];
#pragma unroll
    for (int i = 0; i < 4; ++i)
      af[i] = ld_bf8_8al(&Vt[(wm * 64 + i * 16 + l15) * 44 + quad * 8]);
#pragma unroll
    for (int j = 0; j < 4; ++j)
      wf[j] = ld_bf8_8al(&Pt[(wn * 64 + j * 16 + l15) * 44 + quad * 8]);
#pragma unroll
    for (int i = 0; i < 4; ++i)
#pragma unroll
      for (int j = 0; j < 4; ++j)
        acc[i][j] = __builtin_amdgcn_mfma_f32_16x16x32_bf16(af[i], wf[j], acc[i][j], 0, 0, 0);
    asm volatile("s_waitcnt lgkmcnt(0)" ::: "memory");
    __builtin_amdgcn_sched_barrier(0);
  }

  float* kout = kvp + (size_t)(bh * 4 + split) * (D_H * D_H);
#pragma unroll
  for (int j = 0; j < 4; ++j) {
    const int d = wn * 64 + j * 16 + l15;
#pragma unroll
    for (int i = 0; i < 4; ++i) {
#pragma unroll
      for (int r = 0; r < 4; ++r) {
        const int e = wm * 64 + i * 16 + quad * 4 + r;
        kout[(size_t)e * D_H + d] = acc[i][j][r];
      }
    }
  }
  // z partial over this split's s-range (coalesced s-major reads, L2-hot)
  __syncthreads();
  {
    const int d8 = tid & 15, so = tid >> 4; // 16 d-octets x 16 s-phases
    float za[8] = {};
    for (int s = so; s < 512; s += 16) {
      uint4 u = *(const uint4*)(Pg + (size_t)s * 128 + d8 * 8);
      const short* sp = (const short*)&u;
#pragma unroll
      for (int u2 = 0; u2 < 8; ++u2) za[u2] += bf2f(sp[u2]);
    }
#pragma unroll
    for (int u2 = 0; u2 < 8; ++u2) zl[so * 128 + d8 * 8 + u2] = za[u2];
  }
  __syncthreads();
  if (tid < 128) {
    float sum = 0.f;
#pragma unroll
    for (int k = 0; k < 16; ++k) sum += zl[k * 128 + tid];
    zp[(bh * 4 + split) * D_H + tid] = sum;
  }
}

// ---------------- kv reduce: kvT bf16 = sum of 4 partials; z likewise ----------------
__global__ void kv_reduce(const float* __restrict__ kvp, const float* __restrict__ zp,
                          short* __restrict__ kvT, float* __restrict__ z) {
  const int bh = blockIdx.x;
  const int tid = threadIdx.x; // 256
  const float* k0 = kvp + (size_t)(bh * 4) * (D_H * D_H);
  for (int i = tid; i < D_H * D_H; i += 256) {
    float s = k0[i] + k0[16384 + i] + k0[32768 + i] + k0[49152 + i];
    kvT[(size_t)bh * (D_H * D_H) + i] = f2bf(s);
  }
  if (tid < 128) {
    const float* z0 = zp + bh * 4 * D_H;
    z[bh * D_H + tid] = z0[tid] + z0[D_H + tid] + z0[2 * D_H + tid] + z0[3 * D_H + tid];
  }
}

// ---------------- num/den/divide: att = (pq @ kv) / (pq . z + eps) ----------------
__launch_bounds__(256, 2)
__global__ void attn_kernel(const short* __restrict__ pq, const short* __restrict__ kvT,
                            const float* __restrict__ z, short* __restrict__ att) {
  __shared__ alignas(16) char Lb[65536];
  __shared__ float den_lds[128];
  __shared__ float z_lds[128];
  const int s0 = blockIdx.x * 128; // 16 tiles over S
  const int bh = blockIdx.y;       // 0..127
  const int tid = threadIdx.x;

  const short* Abase = pq + ((size_t)bh * S_LEN + s0) * D_H; // rows = s
  const short* Wbase = kvT + (size_t)bh * (D_H * D_H);       // rows = e, cols = d

  f32x4 acc[4][4] = {};
  core_128<128>(Abase, Wbase, Lb, acc);

  if (tid < 128) z_lds[tid] = z[bh * D_H + tid];
  __syncthreads();
  if (tid < 128) {
    const short* prow = Abase + (size_t)tid * D_H;
    float sum = 0.f;
#pragma unroll
    for (int d = 0; d < D_H; d += 8) {
      bf16x8 vv = *(const bf16x8*)(prow + d);
#pragma unroll
      for (int t = 0; t < 8; ++t) sum += (float)vv[t] * z_lds[d + t];
    }
    den_lds[tid] = sum + 1e-6f;
  }
  __syncthreads();

  const int lane = tid & 63;
  const int wm = (tid >> 6) & 1, wn = tid >> 7;
  const int l15 = lane & 15, quad = lane >> 4;
  const int b = bh >> 3, hd = bh & 7;
#pragma unroll
  for (int j = 0; j < 4; ++j) {
    const int e = wn * 64 + j * 16 + l15;
#pragma unroll
    for (int i = 0; i < 4; ++i) {
#pragma unroll
      for (int r = 0; r < 4; ++r) {
        int mloc = wm * 64 + i * 16 + quad * 4 + r; // s_local
        float a = acc[i][j][r] / den_lds[mloc];
        att[((size_t)(s0 + mloc) * B_SZ + b) * D_MOD + hd * D_H + e] = f2bf(a);
      }
    }
  }
}

// ---------------- out = att @ Wo^T + bo (fp32 out), 256x256 tiles ----------------
__launch_bounds__(512, 1)
__global__ void gemm_out(const short* __restrict__ att, const short* __restrict__ WoB,
                         const float* __restrict__ bo, float* __restrict__ out) {
  __shared__ alignas(16) char Lb[131072];
  const int lin = blockIdx.y * 4 + blockIdx.x; // 0..511
  const int x = lin & 7, q = lin >> 3;         // q 0..63
  const int bn = q & 3;                        // 0..3
  const int bm = x * 16 + (q >> 2);            // 0..127
  const int rowBase = bm * 256, colBase = bn * 256;

  f32x4 acc[8][4] = {};
  core_256<1024>(att + (size_t)rowBase * 1024, WoB + (size_t)colBase * 1024, Lb, acc);

  const int tid = threadIdx.x;
  const int lane = tid & 63;
  const int wave = tid >> 6;
  const int wm = wave & 1, wn = wave >> 1;
  const int l15 = lane & 15, quad = lane >> 4;
#pragma unroll
  for (int j = 0; j < 4; ++j) {
    const int gcol = colBase + wn * 64 + j * 16 + l15;
    const float bval = bo[gcol];
#pragma unroll
    for (int i = 0; i < 8; ++i) {
#pragma unroll
      for (int r = 0; r < 4; ++r) {
        int grow = rowBase + wm * 128 + i * 16 + quad * 4 + r;
        out[(size_t)grow * 1024 + gcol] = acc[i][j][r] + bval;
      }
    }
  }
}

extern "C" void kernel_launch(void* const* d_in, const int* in_sizes, int n_in,
                              void* d_out, int out_size, void* d_ws, size_t ws_size,
                              hipStream_t stream) {
  const float* x  = (const float*)d_in[0];
  const float* Wq = (const float*)d_in[1];
  const float* bq = (const float*)d_in[2];
  const float* Wk = (const float*)d_in[3];
  const float* bk = (const float*)d_in[4];
  const float* Wv = (const float*)d_in[5];
  const float* bv = (const float*)d_in[6];
  const float* Wo = (const float*)d_in[7];
  const float* bo = (const float*)d_in[8];
  float* out = (float*)d_out;

  char* ws = (char*)d_ws;
  short* h    = (short*)(ws);                 // 67,108,864 B (h; then kvp/zp; then att)
  short* Wcat = (short*)(ws + 67108864);      //  8,388,608 B ([Wq;Wk;Wv;Wo] bf16)
  short* pq   = (short*)(ws + 75497472);      // 67,108,864 B  [B,H,S,dh]
  short* pk   = (short*)(ws + 142606336);     // 67,108,864 B  [B,H,S,dh]
  short* pv   = (short*)(ws + 209715200);     // 67,108,864 B  [B,H,S,dh]
  short* kvT  = (short*)(ws + 276824064);     //  4,194,304 B
  float* z    = (float*)(ws + 281018368);     //     65,536 B
  // dead-h-region reuse (after gemm_qkv, before attn):
  float* kvp  = (float*)(ws);                 // 33,554,432 B fp32 partials
  float* zp   = (float*)(ws + 33554432);      //    262,144 B fp32 z partials

  prep_h<<<16384, 256, 0, stream>>>(x, h);
  pack_w<<<4096, 256, 0, stream>>>(Wq, Wk, Wv, Wo, Wcat);
  gemm_qkv<<<dim3(12, 128), 512, 0, stream>>>(h, Wcat, bq, bk, bv, pq, pk, pv);
  kv_part<<<dim3(4, 128), 256, 0, stream>>>(pk, pv, kvp, zp);
  kv_reduce<<<128, 256, 0, stream>>>(kvp, zp, kvT, z);
  attn_kernel<<<dim3(16, 128), 256, 0, stream>>>(pq, kvT, z, h /* att reuses h */);
  gemm_out<<<dim3(4, 128), 512, 0, stream>>>(h, Wcat + 3145728, bo, out);
}